// Round 1
// baseline (2175.939 us; speedup 1.0000x reference)
//
#include <hip/hip_runtime.h>
#include <hip/hip_bf16.h>
#include <math.h>

// Problem constants
#define LL 512
#define BB 8
#define DD 768
#define HH 12
#define DHH 64
#define PP 128

// ---------------------------------------------------------------------------
// Block-wide reduce of two values (sum), 256 threads = 4 waves of 64
__device__ __forceinline__ void block_reduce2(float& a, float& b, float* sbuf) {
#pragma unroll
  for (int off = 32; off > 0; off >>= 1) {
    a += __shfl_down(a, off, 64);
    b += __shfl_down(b, off, 64);
  }
  int wid = threadIdx.x >> 6, lane = threadIdx.x & 63;
  __syncthreads();
  if (lane == 0) { sbuf[wid] = a; sbuf[4 + wid] = b; }
  __syncthreads();
  a = sbuf[0] + sbuf[1] + sbuf[2] + sbuf[3];
  b = sbuf[4] + sbuf[5] + sbuf[6] + sbuf[7];
}

// LayerNorm over D=768, one block per row, 256 threads x 3 elements
__global__ __launch_bounds__(256) void ln_kernel(const float* __restrict__ x,
                                                 const float* __restrict__ w,
                                                 const float* __restrict__ bb,
                                                 float* __restrict__ out) {
  __shared__ float sbuf[8];
  size_t row = blockIdx.x;
  const float* xr = x + row * DD;
  int t = threadIdx.x;
  float v0 = xr[t], v1 = xr[t + 256], v2 = xr[t + 512];
  float s = v0 + v1 + v2;
  float ss = v0 * v0 + v1 * v1 + v2 * v2;
  block_reduce2(s, ss, sbuf);
  float mu = s * (1.0f / DD);
  float var = ss * (1.0f / DD) - mu * mu;
  float r = rsqrtf(var + 1e-5f);
  float* orow = out + row * DD;
  orow[t]       = (v0 - mu) * r * w[t]       + bb[t];
  orow[t + 256] = (v1 - mu) * r * w[t + 256] + bb[t + 256];
  orow[t + 512] = (v2 - mu) * r * w[t + 512] + bb[t + 512];
}

// ---------------------------------------------------------------------------
// Generic fp32 GEMM: C = act(A * B^T + bias) + residual
// A[M,K] lda row-major, B[N,K] ldb row-major ("B^T input"), C[M,N] ldc.
// Batched over blockIdx.z with z = zo*H + zi (H=12): off = zo*s?o + zi*s?i.
// Requires: 64 | (grid-covered M,N); 16 | K. 64x64 tile, 256 thr, 4x4/thread.
__global__ __launch_bounds__(256) void gemm_kernel(
    const float* __restrict__ A, int lda, long sAo, long sAi,
    const float* __restrict__ B, int ldb, long sBo, long sBi,
    float* __restrict__ C, int ldc, long sCo, long sCi,
    const float* __restrict__ bias,
    const float* __restrict__ residual,
    int K, int act) {
  int z = blockIdx.z;
  int zo = z / HH, zi = z - zo * HH;
  A += (size_t)zo * sAo + (size_t)zi * sAi;
  B += (size_t)zo * sBo + (size_t)zi * sBi;
  size_t coff = (size_t)zo * sCo + (size_t)zi * sCi;
  C += coff;

  __shared__ float As[16][68];
  __shared__ float Bs[16][68];
  int tid = threadIdx.x;
  int tx = tid & 15, ty = tid >> 4;
  int m0 = blockIdx.y * 64, n0 = blockIdx.x * 64;
  float acc[4][4] = {};
  int r = tid >> 2, kq = (tid & 3) * 4;

  for (int k0 = 0; k0 < K; k0 += 16) {
    float4 av = *(const float4*)(A + (size_t)(m0 + r) * lda + (k0 + kq));
    float4 bv = *(const float4*)(B + (size_t)(n0 + r) * ldb + (k0 + kq));
    As[kq + 0][r] = av.x; As[kq + 1][r] = av.y; As[kq + 2][r] = av.z; As[kq + 3][r] = av.w;
    Bs[kq + 0][r] = bv.x; Bs[kq + 1][r] = bv.y; Bs[kq + 2][r] = bv.z; Bs[kq + 3][r] = bv.w;
    __syncthreads();
#pragma unroll
    for (int kk = 0; kk < 16; kk++) {
      float4 a4 = *(const float4*)&As[kk][ty * 4];
      float4 b4 = *(const float4*)&Bs[kk][tx * 4];
      float ar[4] = {a4.x, a4.y, a4.z, a4.w};
      float br[4] = {b4.x, b4.y, b4.z, b4.w};
#pragma unroll
      for (int i2 = 0; i2 < 4; i2++)
#pragma unroll
        for (int j2 = 0; j2 < 4; j2++)
          acc[i2][j2] += ar[i2] * br[j2];
    }
    __syncthreads();
  }

  float bs[4] = {0.f, 0.f, 0.f, 0.f};
  if (bias) {
    float4 b4 = *(const float4*)&bias[n0 + tx * 4];
    bs[0] = b4.x; bs[1] = b4.y; bs[2] = b4.z; bs[3] = b4.w;
  }
#pragma unroll
  for (int i2 = 0; i2 < 4; i2++) {
    size_t m = (size_t)(m0 + ty * 4 + i2);
    float vout[4];
#pragma unroll
    for (int j2 = 0; j2 < 4; j2++) {
      float vv = acc[i2][j2] + bs[j2];
      if (act == 1) vv = 0.5f * vv * (1.0f + erff(vv * 0.70710678118654752f));
      vout[j2] = vv;
    }
    if (residual) {
      const float4 r4 = *(const float4*)&residual[coff + m * ldc + n0 + tx * 4];
      vout[0] += r4.x; vout[1] += r4.y; vout[2] += r4.z; vout[3] += r4.w;
    }
    float4 o4 = make_float4(vout[0], vout[1], vout[2], vout[3]);
    *(float4*)&C[m * ldc + n0 + tx * 4] = o4;
  }
}

// ---------------------------------------------------------------------------
// qkv [L*B, 3D] -> q,k,v [B,H,L,Dh]
__global__ __launch_bounds__(256) void split_qkv(const float* __restrict__ qkv,
                                                 float* __restrict__ q,
                                                 float* __restrict__ k,
                                                 float* __restrict__ v) {
  int idx = blockIdx.x * 256 + threadIdx.x;  // over 96*512*64 = 3145728
  int d = idx & 63;
  int l = (idx >> 6) & 511;
  int bh = idx >> 15;            // b*12+h
  int b = bh / HH, h = bh - b * HH;
  size_t src = ((size_t)(l * BB + b)) * (3 * DD) + h * 64 + d;
  q[idx] = qkv[src];
  k[idx] = qkv[src + DD];
  v[idx] = qkv[src + 2 * DD];
}

// ---------------------------------------------------------------------------
// In-place: eout = (t + pe_t_k + pe_t_q) * inv + edge  (t currently in eout)
// One block per (b,i); bdist row cached in LDS, reused across all 12 heads.
__global__ __launch_bounds__(256) void gather_scale(const float* __restrict__ kp,
                                                    const float* __restrict__ qp,
                                                    const int* __restrict__ bdist,
                                                    const float* __restrict__ edge,
                                                    float* __restrict__ eout) {
  int b = blockIdx.x >> 9;
  int i = blockIdx.x & 511;
  __shared__ float qprow[PP];
  __shared__ int idxs[LL];
  int t = threadIdx.x;
  for (int j = t; j < LL; j += 256) idxs[j] = bdist[((size_t)i * LL + j) * BB + b];
  __syncthreads();
  const float inv = 0.125f;  // 1/sqrt(64)
  for (int h = 0; h < HH; h++) {
    int bh = b * HH + h;
    if (t < PP) qprow[t] = qp[((size_t)bh * LL + i) * PP + t];
    __syncthreads();
    for (int j = t; j < LL; j += 256) {
      int p = idxs[j];
      float gk = kp[((size_t)bh * LL + j) * PP + p];
      float gq = qprow[p];
      size_t off = (size_t)bh * (LL * LL) + (size_t)i * LL + j;
      eout[off] = (eout[off] + gk + gq) * inv + edge[off];
    }
    __syncthreads();
  }
}

// ---------------------------------------------------------------------------
// Fused softmax + P@V, one block per (b,h,i) row. scores = edge_out in d_out.
__global__ __launch_bounds__(256) void softmax_pv(const float* __restrict__ scores,
                                                  const float* __restrict__ v,
                                                  float* __restrict__ o) {
  __shared__ float sbuf[8];
  __shared__ float p[LL];
  __shared__ float ored[4][64];
  int bh = blockIdx.x >> 9;
  int i = blockIdx.x & 511;
  const float* srow = scores + (size_t)bh * (LL * LL) + (size_t)i * LL;
  int t = threadIdx.x;
  int wid = t >> 6, lane = t & 63;
  float s0 = srow[t], s1 = srow[t + 256];
  float m = fmaxf(s0, s1);
#pragma unroll
  for (int off = 32; off > 0; off >>= 1) m = fmaxf(m, __shfl_down(m, off, 64));
  if (lane == 0) sbuf[wid] = m;
  __syncthreads();
  m = fmaxf(fmaxf(sbuf[0], sbuf[1]), fmaxf(sbuf[2], sbuf[3]));
  __syncthreads();
  float e0 = expf(s0 - m), e1 = expf(s1 - m);
  p[t] = e0;
  p[t + 256] = e1;
  float s = e0 + e1;
#pragma unroll
  for (int off = 32; off > 0; off >>= 1) s += __shfl_down(s, off, 64);
  if (lane == 0) sbuf[wid] = s;
  __syncthreads();
  s = sbuf[0] + sbuf[1] + sbuf[2] + sbuf[3];
  float rs = 1.0f / s;
  int g = t >> 6, d = t & 63;
  const float* vb = v + (size_t)bh * (LL * DHH);
  float acc = 0.f;
  for (int j = g; j < LL; j += 4) acc += p[j] * vb[(size_t)j * DHH + d];
  ored[g][d] = acc;
  __syncthreads();
  if (g == 0) {
    o[(size_t)bh * (LL * DHH) + (size_t)i * DHH + d] =
        (ored[0][d] + ored[1][d] + ored[2][d] + ored[3][d]) * rs;
  }
}

// o [B,H,L,Dh] -> o_lbd [L*B, D]
__global__ __launch_bounds__(256) void o_transpose(const float* __restrict__ o,
                                                   float* __restrict__ olbd) {
  int idx = blockIdx.x * 256 + threadIdx.x;  // over 3145728, dst index
  int lb = idx / DD;
  int rem = idx - lb * DD;
  int h = rem >> 6, d = rem & 63;
  int l = lb >> 3, b = lb & 7;
  olbd[idx] = o[((size_t)(b * HH + h) * LL + l) * DHH + d];
}

// ---------------------------------------------------------------------------
extern "C" void kernel_launch(void* const* d_in, const int* in_sizes, int n_in,
                              void* d_out, int out_size, void* d_ws, size_t ws_size,
                              hipStream_t stream) {
  const float* x      = (const float*)d_in[0];
  const float* edge   = (const float*)d_in[1];
  const int*   bdist  = (const int*)d_in[2];
  const float* W_in   = (const float*)d_in[3];
  const float* b_in   = (const float*)d_in[4];
  const float* pe_emb = (const float*)d_in[5];
  const float* W_out  = (const float*)d_in[6];
  const float* b_out  = (const float*)d_in[7];
  const float* W1     = (const float*)d_in[8];
  const float* b1     = (const float*)d_in[9];
  const float* W2     = (const float*)d_in[10];
  const float* b2     = (const float*)d_in[11];
  const float* ln1w   = (const float*)d_in[12];
  const float* ln1b   = (const float*)d_in[13];
  const float* ln2w   = (const float*)d_in[14];
  const float* ln2b   = (const float*)d_in[15];

  float* xout = (float*)d_out;                 // [L,B,D] = 3145728
  float* eout = xout + (size_t)LL * BB * DD;   // [B*H,L,L] = 25165824 (== scores)

  // Workspace layout (floats). Total 38,043,648 floats = 152.2 MB.
  float* ws   = (float*)d_ws;
  float* xn   = ws;                  // 3,145,728  (reused for ln2 output)
  float* qkv  = ws + 3145728;        // 9,437,184
  float* olbd = qkv;                 //   reuse of qkv after split
  float* x1   = qkv + 3145728;       //   reuse of qkv region
  float* pe   = ws + 12582912;       //   294,912
  float* q    = ws + 12877824;       // 3,145,728
  float* k    = ws + 16023552;       // 3,145,728
  float* vv   = ws + 19169280;       // 3,145,728
  float* kp   = ws + 22315008;       // 6,291,456
  float* qp   = ws + 28606464;       // 6,291,456
  float* obh  = ws + 34897920;       // 3,145,728
  float* ff1  = kp;                  //   reuse of kp+qp region (12,582,912)

  // 1) LN1
  ln_kernel<<<4096, 256, 0, stream>>>(x, ln1w, ln1b, xn);
  // 2) qkv = xn @ W_in^T + b_in      [4096 x 2304, K=768]
  gemm_kernel<<<dim3(36, 64, 1), 256, 0, stream>>>(
      xn, DD, 0, 0, W_in, DD, 0, 0, qkv, 3 * DD, 0, 0, b_in, nullptr, DD, 0);
  // 3) pe_proj = pe_emb @ W_in^T + b_in   [128 x 2304, K=768]
  gemm_kernel<<<dim3(36, 2, 1), 256, 0, stream>>>(
      pe_emb, DD, 0, 0, W_in, DD, 0, 0, pe, 3 * DD, 0, 0, b_in, nullptr, DD, 0);
  // 4) split to q,k,v [B,H,L,Dh]
  split_qkv<<<12288, 256, 0, stream>>>(qkv, q, k, vv);
  // 5) t = q k^T per head -> eout       [512x512, K=64] x 96
  gemm_kernel<<<dim3(8, 8, 96), 256, 0, stream>>>(
      q, DHH, (long)HH * LL * DHH, (long)LL * DHH,
      k, DHH, (long)HH * LL * DHH, (long)LL * DHH,
      eout, LL, (long)HH * LL * LL, (long)LL * LL, nullptr, nullptr, DHH, 0);
  // 6) kp = k @ pe_q^T   [512x128, K=64] x 96  (pe_q slice of pe, ldb=2304)
  gemm_kernel<<<dim3(2, 8, 96), 256, 0, stream>>>(
      k, DHH, (long)HH * LL * DHH, (long)LL * DHH,
      pe, 3 * DD, 0, 64,
      kp, PP, (long)HH * LL * PP, (long)LL * PP, nullptr, nullptr, DHH, 0);
  // 7) qp = q @ pe_k^T
  gemm_kernel<<<dim3(2, 8, 96), 256, 0, stream>>>(
      q, DHH, (long)HH * LL * DHH, (long)LL * DHH,
      pe + DD, 3 * DD, 0, 64,
      qp, PP, (long)HH * LL * PP, (long)LL * PP, nullptr, nullptr, DHH, 0);
  // 8) eout = (t + gathers)*inv + edge   (scores == edge_out)
  gather_scale<<<4096, 256, 0, stream>>>(kp, qp, bdist, edge, eout);
  // 9) fused softmax + PV -> obh [B,H,L,Dh]
  softmax_pv<<<49152, 256, 0, stream>>>(eout, vv, obh);
  // 10) transpose to [L*B, D]
  o_transpose<<<12288, 256, 0, stream>>>(obh, olbd);
  // 11) x1 = olbd @ W_out^T + b_out + x
  gemm_kernel<<<dim3(12, 64, 1), 256, 0, stream>>>(
      olbd, DD, 0, 0, W_out, DD, 0, 0, x1, DD, 0, 0, b_out, x, DD, 0);
  // 12) LN2 (into xn, reused)
  ln_kernel<<<4096, 256, 0, stream>>>(x1, ln2w, ln2b, xn);
  // 13) ff1 = gelu(xn @ W1^T + b1)    [4096 x 3072, K=768]
  gemm_kernel<<<dim3(48, 64, 1), 256, 0, stream>>>(
      xn, DD, 0, 0, W1, DD, 0, 0, ff1, 4 * DD, 0, 0, b1, nullptr, DD, 1);
  // 14) x_out = ff1 @ W2^T + b2 + x1  [4096 x 768, K=3072]
  gemm_kernel<<<dim3(12, 64, 1), 256, 0, stream>>>(
      ff1, 4 * DD, 0, 0, W2, 4 * DD, 0, 0, xout, DD, 0, 0, b2, x1, 4 * DD, 0);
}

// Round 2
// 1227.258 us; speedup vs baseline: 1.7730x; 1.7730x over previous
//
#include <hip/hip_runtime.h>
#include <hip/hip_bf16.h>
#include <math.h>

// Problem constants
#define LL 512
#define BB 8
#define DD 768
#define HH 12
#define DHH 64
#define PP 128

// ---------------------------------------------------------------------------
// Block-wide reduce of two values (sum), 256 threads = 4 waves of 64
__device__ __forceinline__ void block_reduce2(float& a, float& b, float* sbuf) {
#pragma unroll
  for (int off = 32; off > 0; off >>= 1) {
    a += __shfl_down(a, off, 64);
    b += __shfl_down(b, off, 64);
  }
  int wid = threadIdx.x >> 6, lane = threadIdx.x & 63;
  __syncthreads();
  if (lane == 0) { sbuf[wid] = a; sbuf[4 + wid] = b; }
  __syncthreads();
  a = sbuf[0] + sbuf[1] + sbuf[2] + sbuf[3];
  b = sbuf[4] + sbuf[5] + sbuf[6] + sbuf[7];
}

// LayerNorm over D=768, one block per row, 256 threads x 3 elements
__global__ __launch_bounds__(256) void ln_kernel(const float* __restrict__ x,
                                                 const float* __restrict__ w,
                                                 const float* __restrict__ bb,
                                                 float* __restrict__ out) {
  __shared__ float sbuf[8];
  size_t row = blockIdx.x;
  const float* xr = x + row * DD;
  int t = threadIdx.x;
  float v0 = xr[t], v1 = xr[t + 256], v2 = xr[t + 512];
  float s = v0 + v1 + v2;
  float ss = v0 * v0 + v1 * v1 + v2 * v2;
  block_reduce2(s, ss, sbuf);
  float mu = s * (1.0f / DD);
  float var = ss * (1.0f / DD) - mu * mu;
  float r = rsqrtf(var + 1e-5f);
  float* orow = out + row * DD;
  orow[t]       = (v0 - mu) * r * w[t]       + bb[t];
  orow[t + 256] = (v1 - mu) * r * w[t + 256] + bb[t + 256];
  orow[t + 512] = (v2 - mu) * r * w[t + 512] + bb[t + 512];
}

// ---------------------------------------------------------------------------
// Generic fp32 GEMM: C = act(A * B^T + bias) + residual
// A[M,K] lda row-major, B[N,K] ldb row-major ("B^T input"), C[M,N] ldc.
// Batched over blockIdx.z with z = zo*H + zi (H=12): off = zo*s?o + zi*s?i.
// Requires: 64 | (grid-covered M,N); 16 | K. 64x64 tile, 256 thr, 4x4/thread.
__global__ __launch_bounds__(256) void gemm_kernel(
    const float* __restrict__ A, int lda, long sAo, long sAi,
    const float* __restrict__ B, int ldb, long sBo, long sBi,
    float* __restrict__ C, int ldc, long sCo, long sCi,
    const float* __restrict__ bias,
    const float* __restrict__ residual,
    int K, int act) {
  int z = blockIdx.z;
  int zo = z / HH, zi = z - zo * HH;
  A += (size_t)zo * sAo + (size_t)zi * sAi;
  B += (size_t)zo * sBo + (size_t)zi * sBi;
  size_t coff = (size_t)zo * sCo + (size_t)zi * sCi;
  C += coff;

  __shared__ float As[16][68];
  __shared__ float Bs[16][68];
  int tid = threadIdx.x;
  int tx = tid & 15, ty = tid >> 4;
  int m0 = blockIdx.y * 64, n0 = blockIdx.x * 64;
  float acc[4][4] = {};
  int r = tid >> 2, kq = (tid & 3) * 4;

  for (int k0 = 0; k0 < K; k0 += 16) {
    float4 av = *(const float4*)(A + (size_t)(m0 + r) * lda + (k0 + kq));
    float4 bv = *(const float4*)(B + (size_t)(n0 + r) * ldb + (k0 + kq));
    As[kq + 0][r] = av.x; As[kq + 1][r] = av.y; As[kq + 2][r] = av.z; As[kq + 3][r] = av.w;
    Bs[kq + 0][r] = bv.x; Bs[kq + 1][r] = bv.y; Bs[kq + 2][r] = bv.z; Bs[kq + 3][r] = bv.w;
    __syncthreads();
#pragma unroll
    for (int kk = 0; kk < 16; kk++) {
      float4 a4 = *(const float4*)&As[kk][ty * 4];
      float4 b4 = *(const float4*)&Bs[kk][tx * 4];
      float ar[4] = {a4.x, a4.y, a4.z, a4.w};
      float br[4] = {b4.x, b4.y, b4.z, b4.w};
#pragma unroll
      for (int i2 = 0; i2 < 4; i2++)
#pragma unroll
        for (int j2 = 0; j2 < 4; j2++)
          acc[i2][j2] += ar[i2] * br[j2];
    }
    __syncthreads();
  }

  float bs[4] = {0.f, 0.f, 0.f, 0.f};
  if (bias) {
    float4 b4 = *(const float4*)&bias[n0 + tx * 4];
    bs[0] = b4.x; bs[1] = b4.y; bs[2] = b4.z; bs[3] = b4.w;
  }
#pragma unroll
  for (int i2 = 0; i2 < 4; i2++) {
    size_t m = (size_t)(m0 + ty * 4 + i2);
    float vout[4];
#pragma unroll
    for (int j2 = 0; j2 < 4; j2++) {
      float vv = acc[i2][j2] + bs[j2];
      if (act == 1) vv = 0.5f * vv * (1.0f + erff(vv * 0.70710678118654752f));
      vout[j2] = vv;
    }
    if (residual) {
      const float4 r4 = *(const float4*)&residual[coff + m * ldc + n0 + tx * 4];
      vout[0] += r4.x; vout[1] += r4.y; vout[2] += r4.z; vout[3] += r4.w;
    }
    float4 o4 = make_float4(vout[0], vout[1], vout[2], vout[3]);
    *(float4*)&C[m * ldc + n0 + tx * 4] = o4;
  }
}

// ---------------------------------------------------------------------------
// qkv [L*B, 3D] -> q,k,v [B,H,L,Dh]
__global__ __launch_bounds__(256) void split_qkv(const float* __restrict__ qkv,
                                                 float* __restrict__ q,
                                                 float* __restrict__ k,
                                                 float* __restrict__ v) {
  int idx = blockIdx.x * 256 + threadIdx.x;  // over 96*512*64 = 3145728
  int d = idx & 63;
  int l = (idx >> 6) & 511;
  int bh = idx >> 15;            // b*12+h
  int b = bh / HH, h = bh - b * HH;
  size_t src = ((size_t)(l * BB + b)) * (3 * DD) + h * 64 + d;
  q[idx] = qkv[src];
  k[idx] = qkv[src + DD];
  v[idx] = qkv[src + 2 * DD];
}

// ---------------------------------------------------------------------------
// In-place: eout = (t + pe_t_k + pe_t_q) * inv + edge  (t currently in eout)
// One block per (b,i); bdist row cached in LDS, reused across all 12 heads.
__global__ __launch_bounds__(256) void gather_scale(const float* __restrict__ kp,
                                                    const float* __restrict__ qp,
                                                    const int* __restrict__ bdist,
                                                    const float* __restrict__ edge,
                                                    float* __restrict__ eout) {
  int b = blockIdx.x >> 9;
  int i = blockIdx.x & 511;
  __shared__ float qprow[PP];
  __shared__ int idxs[LL];
  int t = threadIdx.x;
  for (int j = t; j < LL; j += 256) idxs[j] = bdist[((size_t)i * LL + j) * BB + b];
  __syncthreads();
  const float inv = 0.125f;  // 1/sqrt(64)
  for (int h = 0; h < HH; h++) {
    int bh = b * HH + h;
    if (t < PP) qprow[t] = qp[((size_t)bh * LL + i) * PP + t];
    __syncthreads();
    for (int j = t; j < LL; j += 256) {
      int p = idxs[j];
      float gk = kp[((size_t)bh * LL + j) * PP + p];
      float gq = qprow[p];
      size_t off = (size_t)bh * (LL * LL) + (size_t)i * LL + j;
      eout[off] = (eout[off] + gk + gq) * inv + edge[off];
    }
    __syncthreads();
  }
}

// ---------------------------------------------------------------------------
// Fused softmax + P@V, tiled. One block per (bh, 64-row i-tile), 256 threads.
// Phase A: per-row max & exp-sum (float4 loads, wave shfl reduce).
// Phase B: 8 j-tiles of 64: S-tile -> exp -> P^T in LDS; V-tile in LDS;
//          4x4-register-tiled FMA. Writes O directly in [L,B,D] layout.
__global__ __launch_bounds__(256) void softmax_pv_tiled(
    const float* __restrict__ scores, const float* __restrict__ v,
    float* __restrict__ olbd) {
  int bh = blockIdx.y;            // 0..95
  int i0 = blockIdx.x * 64;       // 8 i-tiles
  int b = bh / HH, h = bh - b * HH;
  __shared__ float Pt[64][66];    // P transposed: Pt[k][i]; pad 66 -> 2-way-free reads
  __shared__ float Vt[64][72];    // V row-major: Vt[k][d]; pad 72 keeps float4 align
  __shared__ float smax[64], srs[64];
  int t = threadIdx.x;
  int wid = t >> 6, lane = t & 63;
  const float* sbase = scores + (size_t)bh * (LL * LL);

  // Phase A: stats for rows (relative) wid*16 .. wid*16+15
  for (int r = wid * 16; r < wid * 16 + 16; r++) {
    const float* srow = sbase + (size_t)(i0 + r) * LL + lane * 8;
    float4 a = *(const float4*)srow;
    float4 c = *(const float4*)(srow + 4);
    float m = fmaxf(fmaxf(fmaxf(a.x, a.y), fmaxf(a.z, a.w)),
                    fmaxf(fmaxf(c.x, c.y), fmaxf(c.z, c.w)));
#pragma unroll
    for (int off = 1; off < 64; off <<= 1) m = fmaxf(m, __shfl_xor(m, off, 64));
    float s = expf(a.x - m) + expf(a.y - m) + expf(a.z - m) + expf(a.w - m) +
              expf(c.x - m) + expf(c.y - m) + expf(c.z - m) + expf(c.w - m);
#pragma unroll
    for (int off = 1; off < 64; off <<= 1) s += __shfl_xor(s, off, 64);
    if (lane == 0) { smax[r] = m; srs[r] = 1.0f / s; }
  }
  __syncthreads();

  float acc[4][4] = {};
  int tx = t & 15, ty = t >> 4;
  const float* vb = v + (size_t)bh * (LL * DHH);
  int c4 = (t & 15) * 4, r0 = t >> 4;

  for (int jt = 0; jt < 8; jt++) {
    int j0 = jt * 64;
#pragma unroll
    for (int rr = 0; rr < 4; rr++) {
      int r = r0 + rr * 16;
      float4 s4 = *(const float4*)(sbase + (size_t)(i0 + r) * LL + j0 + c4);
      float m = smax[r], rs = srs[r];
      Pt[c4 + 0][r] = expf(s4.x - m) * rs;
      Pt[c4 + 1][r] = expf(s4.y - m) * rs;
      Pt[c4 + 2][r] = expf(s4.z - m) * rs;
      Pt[c4 + 3][r] = expf(s4.w - m) * rs;
      float4 v4 = *(const float4*)(vb + (size_t)(j0 + r) * DHH + c4);
      *(float4*)&Vt[r][c4] = v4;
    }
    __syncthreads();
#pragma unroll 8
    for (int kk = 0; kk < 64; kk++) {
      float4 a4 = *(const float4*)&Pt[kk][ty * 4];
      float4 b4 = *(const float4*)&Vt[kk][tx * 4];
      float ar[4] = {a4.x, a4.y, a4.z, a4.w};
      float br[4] = {b4.x, b4.y, b4.z, b4.w};
#pragma unroll
      for (int i2 = 0; i2 < 4; i2++)
#pragma unroll
        for (int j2 = 0; j2 < 4; j2++)
          acc[i2][j2] += ar[i2] * br[j2];
    }
    __syncthreads();
  }

  // Write O directly in [L,B,D] layout: olbd[(i*B + b)*D + h*64 + d]
#pragma unroll
  for (int i2 = 0; i2 < 4; i2++) {
    int i = i0 + ty * 4 + i2;
    *(float4*)&olbd[((size_t)i * BB + b) * DD + h * 64 + tx * 4] =
        make_float4(acc[i2][0], acc[i2][1], acc[i2][2], acc[i2][3]);
  }
}

// ---------------------------------------------------------------------------
extern "C" void kernel_launch(void* const* d_in, const int* in_sizes, int n_in,
                              void* d_out, int out_size, void* d_ws, size_t ws_size,
                              hipStream_t stream) {
  const float* x      = (const float*)d_in[0];
  const float* edge   = (const float*)d_in[1];
  const int*   bdist  = (const int*)d_in[2];
  const float* W_in   = (const float*)d_in[3];
  const float* b_in   = (const float*)d_in[4];
  const float* pe_emb = (const float*)d_in[5];
  const float* W_out  = (const float*)d_in[6];
  const float* b_out  = (const float*)d_in[7];
  const float* W1     = (const float*)d_in[8];
  const float* b1     = (const float*)d_in[9];
  const float* W2     = (const float*)d_in[10];
  const float* b2     = (const float*)d_in[11];
  const float* ln1w   = (const float*)d_in[12];
  const float* ln1b   = (const float*)d_in[13];
  const float* ln2w   = (const float*)d_in[14];
  const float* ln2b   = (const float*)d_in[15];

  float* xout = (float*)d_out;                 // [L,B,D] = 3145728
  float* eout = xout + (size_t)LL * BB * DD;   // [B*H,L,L] = 25165824 (== scores)

  // Workspace layout (floats). Total <= 38,043,648 floats = 152.2 MB.
  float* ws   = (float*)d_ws;
  float* xn   = ws;                  // 3,145,728  (reused for ln2 output)
  float* qkv  = ws + 3145728;        // 9,437,184
  float* olbd = qkv;                 //   reuse of qkv after split
  float* x1   = qkv + 3145728;       //   reuse of qkv region
  float* pe   = ws + 12582912;       //   294,912
  float* q    = ws + 12877824;       // 3,145,728
  float* k    = ws + 16023552;       // 3,145,728
  float* vv   = ws + 19169280;       // 3,145,728
  float* kp   = ws + 22315008;       // 6,291,456
  float* qp   = ws + 28606464;       // 6,291,456
  float* ff1  = kp;                  //   reuse of kp+qp region (12,582,912)

  // 1) LN1
  ln_kernel<<<4096, 256, 0, stream>>>(x, ln1w, ln1b, xn);
  // 2) qkv = xn @ W_in^T + b_in      [4096 x 2304, K=768]
  gemm_kernel<<<dim3(36, 64, 1), 256, 0, stream>>>(
      xn, DD, 0, 0, W_in, DD, 0, 0, qkv, 3 * DD, 0, 0, b_in, nullptr, DD, 0);
  // 3) pe_proj = pe_emb @ W_in^T + b_in   [128 x 2304, K=768]
  gemm_kernel<<<dim3(36, 2, 1), 256, 0, stream>>>(
      pe_emb, DD, 0, 0, W_in, DD, 0, 0, pe, 3 * DD, 0, 0, b_in, nullptr, DD, 0);
  // 4) split to q,k,v [B,H,L,Dh]
  split_qkv<<<12288, 256, 0, stream>>>(qkv, q, k, vv);
  // 5) t = q k^T per head -> eout       [512x512, K=64] x 96
  gemm_kernel<<<dim3(8, 8, 96), 256, 0, stream>>>(
      q, DHH, (long)HH * LL * DHH, (long)LL * DHH,
      k, DHH, (long)HH * LL * DHH, (long)LL * DHH,
      eout, LL, (long)HH * LL * LL, (long)LL * LL, nullptr, nullptr, DHH, 0);
  // 6) kp = k @ pe_q^T   [512x128, K=64] x 96  (pe_q slice of pe, ldb=2304)
  gemm_kernel<<<dim3(2, 8, 96), 256, 0, stream>>>(
      k, DHH, (long)HH * LL * DHH, (long)LL * DHH,
      pe, 3 * DD, 0, 64,
      kp, PP, (long)HH * LL * PP, (long)LL * PP, nullptr, nullptr, DHH, 0);
  // 7) qp = q @ pe_k^T
  gemm_kernel<<<dim3(2, 8, 96), 256, 0, stream>>>(
      q, DHH, (long)HH * LL * DHH, (long)LL * DHH,
      pe + DD, 3 * DD, 0, 64,
      qp, PP, (long)HH * LL * PP, (long)LL * PP, nullptr, nullptr, DHH, 0);
  // 8) eout = (t + gathers)*inv + edge   (scores == edge_out)
  gather_scale<<<4096, 256, 0, stream>>>(kp, qp, bdist, edge, eout);
  // 9) fused softmax + PV -> olbd [L,B,D] directly
  softmax_pv_tiled<<<dim3(8, 96), 256, 0, stream>>>(eout, vv, olbd);
  // 11) x1 = olbd @ W_out^T + b_out + x
  gemm_kernel<<<dim3(12, 64, 1), 256, 0, stream>>>(
      olbd, DD, 0, 0, W_out, DD, 0, 0, x1, DD, 0, 0, b_out, x, DD, 0);
  // 12) LN2 (into xn, reused)
  ln_kernel<<<4096, 256, 0, stream>>>(x1, ln2w, ln2b, xn);
  // 13) ff1 = gelu(xn @ W1^T + b1)    [4096 x 3072, K=768]
  gemm_kernel<<<dim3(48, 64, 1), 256, 0, stream>>>(
      xn, DD, 0, 0, W1, DD, 0, 0, ff1, 4 * DD, 0, 0, b1, nullptr, DD, 1);
  // 14) x_out = ff1 @ W2^T + b2 + x1  [4096 x 768, K=3072]
  gemm_kernel<<<dim3(12, 64, 1), 256, 0, stream>>>(
      ff1, 4 * DD, 0, 0, W2, 4 * DD, 0, 0, xout, DD, 0, 0, b2, x1, 4 * DD, 0);
}

// Round 3
// 586.950 us; speedup vs baseline: 3.7072x; 2.0909x over previous
//
#include <hip/hip_runtime.h>
#include <hip/hip_bf16.h>
#include <math.h>

// Problem constants
#define LL 512
#define BB 8
#define DD 768
#define HH 12
#define DHH 64
#define PP 128

typedef unsigned short u16;
typedef unsigned int u32;
typedef __attribute__((ext_vector_type(8))) short bf16x8;
typedef __attribute__((ext_vector_type(4))) float f32x4;

__device__ __forceinline__ u16 f2bf(float f) {
  u32 u = __float_as_uint(f);
  u32 r = (u + 0x7fffu + ((u >> 16) & 1u)) >> 16;
  return (u16)r;
}

#define GLDS(g, l)                                                             \
  __builtin_amdgcn_global_load_lds(                                            \
      (const __attribute__((address_space(1))) void*)(g),                      \
      (__attribute__((address_space(3))) void*)(l), 16, 0, 0)

// ---------------------------------------------------------------------------
// Block-wide reduce of two values (sum), 256 threads = 4 waves of 64
__device__ __forceinline__ void block_reduce2(float& a, float& b, float* sbuf) {
#pragma unroll
  for (int off = 32; off > 0; off >>= 1) {
    a += __shfl_down(a, off, 64);
    b += __shfl_down(b, off, 64);
  }
  int wid = threadIdx.x >> 6, lane = threadIdx.x & 63;
  __syncthreads();
  if (lane == 0) { sbuf[wid] = a; sbuf[4 + wid] = b; }
  __syncthreads();
  a = sbuf[0] + sbuf[1] + sbuf[2] + sbuf[3];
  b = sbuf[4] + sbuf[5] + sbuf[6] + sbuf[7];
}

// LayerNorm over D=768, one block per row, 256 threads x 3, bf16 output
__global__ __launch_bounds__(256) void ln_bf16(const float* __restrict__ x,
                                               const float* __restrict__ w,
                                               const float* __restrict__ bb,
                                               u16* __restrict__ out) {
  __shared__ float sbuf[8];
  size_t row = blockIdx.x;
  const float* xr = x + row * DD;
  int t = threadIdx.x;
  float v0 = xr[t], v1 = xr[t + 256], v2 = xr[t + 512];
  float s = v0 + v1 + v2;
  float ss = v0 * v0 + v1 * v1 + v2 * v2;
  block_reduce2(s, ss, sbuf);
  float mu = s * (1.0f / DD);
  float var = ss * (1.0f / DD) - mu * mu;
  float r = rsqrtf(var + 1e-5f);
  u16* orow = out + row * DD;
  orow[t]       = f2bf((v0 - mu) * r * w[t]       + bb[t]);
  orow[t + 256] = f2bf((v1 - mu) * r * w[t + 256] + bb[t + 256]);
  orow[t + 512] = f2bf((v2 - mu) * r * w[t + 512] + bb[t + 512]);
}

// fp32 -> bf16 conversion, grid covers n exactly, 4 elements/thread
__global__ __launch_bounds__(256) void f2b_kernel(const float* __restrict__ in,
                                                  u16* __restrict__ out) {
  int idx = blockIdx.x * 256 + threadIdx.x;
  float4 v = *(const float4*)(in + (size_t)idx * 4);
  u32 lo = (u32)f2bf(v.x) | ((u32)f2bf(v.y) << 16);
  u32 hi = (u32)f2bf(v.z) | ((u32)f2bf(v.w) << 16);
  *(uint2*)(out + (size_t)idx * 4) = make_uint2(lo, hi);
}

// ---------------------------------------------------------------------------
// bf16 MFMA GEMM: C = act(A * B^T + bias) [+ residual]
// A[M,K] bf16 row-major (lda), B[N,K] bf16 row-major (ldb), C[M,N] (ldc)
// fp32 or bf16 out. 128x128 tile, BK=32, 4 waves 2x2, global_load_lds staging.
// Requires 128 | M,N and 32 | K.
template <int ACT, int OBF, int RES>
__global__ __launch_bounds__(256) void gemm_mfma(
    const u16* __restrict__ A, int lda, const u16* __restrict__ B, int ldb,
    void* __restrict__ Cv, int ldc, const float* __restrict__ bias,
    const float* __restrict__ residual, int K) {
  __shared__ __align__(16) u16 Asl[128 * 32];
  __shared__ __align__(16) u16 Bsl[128 * 32];
  int t = threadIdx.x;
  int m0 = blockIdx.y * 128, n0 = blockIdx.x * 128;
  int lane = t & 63, w = t >> 6;
  int wr = w >> 1, wc = w & 1;         // 2x2 wave grid, 64x64 per wave
  int lr = lane & 15, lg = lane >> 4;  // frag row/col, k-group

  f32x4 acc[4][4] = {};

  // staging addresses: thread t covers tile row t>>2 (and +64), k-cols (t&3)*8
  const u16* Ag0 = A + (size_t)(m0 + (t >> 2)) * lda + (t & 3) * 8;
  const u16* Ag1 = A + (size_t)(m0 + 64 + (t >> 2)) * lda + (t & 3) * 8;
  const u16* Bg0 = B + (size_t)(n0 + (t >> 2)) * ldb + (t & 3) * 8;
  const u16* Bg1 = B + (size_t)(n0 + 64 + (t >> 2)) * ldb + (t & 3) * 8;
  u16* Ad0 = &Asl[t * 8];
  u16* Ad1 = &Asl[2048 + t * 8];
  u16* Bd0 = &Bsl[t * 8];
  u16* Bd1 = &Bsl[2048 + t * 8];

  for (int k0 = 0; k0 < K; k0 += 32) {
    GLDS(Ag0 + k0, Ad0);
    GLDS(Ag1 + k0, Ad1);
    GLDS(Bg0 + k0, Bd0);
    GLDS(Bg1 + k0, Bd1);
    __syncthreads();
    bf16x8 a[4], b[4];
#pragma unroll
    for (int i = 0; i < 4; i++)
      a[i] = *(const bf16x8*)&Asl[(wr * 64 + i * 16 + lr) * 32 + lg * 8];
#pragma unroll
    for (int j = 0; j < 4; j++)
      b[j] = *(const bf16x8*)&Bsl[(wc * 64 + j * 16 + lr) * 32 + lg * 8];
#pragma unroll
    for (int i = 0; i < 4; i++)
#pragma unroll
      for (int j = 0; j < 4; j++)
        asm volatile("v_mfma_f32_16x16x32_bf16 %0, %1, %2, %0"
                     : "+v"(acc[i][j])
                     : "v"(a[i]), "v"(b[j]));
    __syncthreads();
  }
  asm volatile("s_nop 7\n\ts_nop 7" ::);  // MFMA->VALU hazard insurance

  float* Cf = (float*)Cv;
  u16* Cb = (u16*)Cv;
#pragma unroll
  for (int i = 0; i < 4; i++) {
#pragma unroll
    for (int r = 0; r < 4; r++) {
      int row = m0 + wr * 64 + i * 16 + lg * 4 + r;
#pragma unroll
      for (int j = 0; j < 4; j++) {
        int col = n0 + wc * 64 + j * 16 + lr;
        float vv = acc[i][j][r] + bias[col];
        if (ACT) vv = 0.5f * vv * (1.0f + erff(vv * 0.70710678118654752f));
        if (RES) vv += residual[(size_t)row * ldc + col];
        if (OBF) Cb[(size_t)row * ldc + col] = f2bf(vv);
        else     Cf[(size_t)row * ldc + col] = vv;
      }
    }
  }
}

// ---------------------------------------------------------------------------
// Generic fp32 GEMM (kept for attention-path GEMMs): C = A*B^T (+bias)
__global__ __launch_bounds__(256) void gemm_kernel(
    const float* __restrict__ A, int lda, long sAo, long sAi,
    const float* __restrict__ B, int ldb, long sBo, long sBi,
    float* __restrict__ C, int ldc, long sCo, long sCi,
    const float* __restrict__ bias,
    const float* __restrict__ residual,
    int K, int act) {
  int z = blockIdx.z;
  int zo = z / HH, zi = z - zo * HH;
  A += (size_t)zo * sAo + (size_t)zi * sAi;
  B += (size_t)zo * sBo + (size_t)zi * sBi;
  size_t coff = (size_t)zo * sCo + (size_t)zi * sCi;
  C += coff;

  __shared__ float As[16][68];
  __shared__ float Bs[16][68];
  int tid = threadIdx.x;
  int tx = tid & 15, ty = tid >> 4;
  int m0 = blockIdx.y * 64, n0 = blockIdx.x * 64;
  float acc[4][4] = {};
  int r = tid >> 2, kq = (tid & 3) * 4;

  for (int k0 = 0; k0 < K; k0 += 16) {
    float4 av = *(const float4*)(A + (size_t)(m0 + r) * lda + (k0 + kq));
    float4 bv = *(const float4*)(B + (size_t)(n0 + r) * ldb + (k0 + kq));
    As[kq + 0][r] = av.x; As[kq + 1][r] = av.y; As[kq + 2][r] = av.z; As[kq + 3][r] = av.w;
    Bs[kq + 0][r] = bv.x; Bs[kq + 1][r] = bv.y; Bs[kq + 2][r] = bv.z; Bs[kq + 3][r] = bv.w;
    __syncthreads();
#pragma unroll
    for (int kk = 0; kk < 16; kk++) {
      float4 a4 = *(const float4*)&As[kk][ty * 4];
      float4 b4 = *(const float4*)&Bs[kk][tx * 4];
      float ar[4] = {a4.x, a4.y, a4.z, a4.w};
      float br[4] = {b4.x, b4.y, b4.z, b4.w};
#pragma unroll
      for (int i2 = 0; i2 < 4; i2++)
#pragma unroll
        for (int j2 = 0; j2 < 4; j2++)
          acc[i2][j2] += ar[i2] * br[j2];
    }
    __syncthreads();
  }

  float bs[4] = {0.f, 0.f, 0.f, 0.f};
  if (bias) {
    float4 b4 = *(const float4*)&bias[n0 + tx * 4];
    bs[0] = b4.x; bs[1] = b4.y; bs[2] = b4.z; bs[3] = b4.w;
  }
#pragma unroll
  for (int i2 = 0; i2 < 4; i2++) {
    size_t m = (size_t)(m0 + ty * 4 + i2);
    float vout[4];
#pragma unroll
    for (int j2 = 0; j2 < 4; j2++) vout[j2] = acc[i2][j2] + bs[j2];
    if (residual) {
      const float4 r4 = *(const float4*)&residual[coff + m * ldc + n0 + tx * 4];
      vout[0] += r4.x; vout[1] += r4.y; vout[2] += r4.z; vout[3] += r4.w;
    }
    *(float4*)&C[m * ldc + n0 + tx * 4] =
        make_float4(vout[0], vout[1], vout[2], vout[3]);
  }
}

// ---------------------------------------------------------------------------
// qkv [L*B, 3D] fp32 -> q,k,v [B,H,L,Dh] fp32
__global__ __launch_bounds__(256) void split_qkv(const float* __restrict__ qkv,
                                                 float* __restrict__ q,
                                                 float* __restrict__ k,
                                                 float* __restrict__ v) {
  int idx = blockIdx.x * 256 + threadIdx.x;
  int d = idx & 63;
  int l = (idx >> 6) & 511;
  int bh = idx >> 15;
  int b = bh / HH, h = bh - b * HH;
  size_t src = ((size_t)(l * BB + b)) * (3 * DD) + h * 64 + d;
  q[idx] = qkv[src];
  k[idx] = qkv[src + DD];
  v[idx] = qkv[src + 2 * DD];
}

// ---------------------------------------------------------------------------
// In-place: eout = (t + pe_t_k + pe_t_q) * inv + edge  (t currently in eout)
__global__ __launch_bounds__(256) void gather_scale(const float* __restrict__ kp,
                                                    const float* __restrict__ qp,
                                                    const int* __restrict__ bdist,
                                                    const float* __restrict__ edge,
                                                    float* __restrict__ eout) {
  int b = blockIdx.x >> 9;
  int i = blockIdx.x & 511;
  __shared__ float qprow[PP];
  __shared__ int idxs[LL];
  int t = threadIdx.x;
  for (int j = t; j < LL; j += 256) idxs[j] = bdist[((size_t)i * LL + j) * BB + b];
  __syncthreads();
  const float inv = 0.125f;
  for (int h = 0; h < HH; h++) {
    int bh = b * HH + h;
    if (t < PP) qprow[t] = qp[((size_t)bh * LL + i) * PP + t];
    __syncthreads();
    for (int j = t; j < LL; j += 256) {
      int p = idxs[j];
      float gk = kp[((size_t)bh * LL + j) * PP + p];
      float gq = qprow[p];
      size_t off = (size_t)bh * (LL * LL) + (size_t)i * LL + j;
      eout[off] = (eout[off] + gk + gq) * inv + edge[off];
    }
    __syncthreads();
  }
}

// ---------------------------------------------------------------------------
// Fused softmax + P@V, tiled; writes O in [L,B,D] layout as bf16.
__global__ __launch_bounds__(256) void softmax_pv_tiled(
    const float* __restrict__ scores, const float* __restrict__ v,
    u16* __restrict__ olbd) {
  int bh = blockIdx.y;
  int i0 = blockIdx.x * 64;
  int b = bh / HH, h = bh - b * HH;
  __shared__ float Pt[64][66];
  __shared__ float Vt[64][72];
  __shared__ float smax[64], srs[64];
  int t = threadIdx.x;
  int wid = t >> 6, lane = t & 63;
  const float* sbase = scores + (size_t)bh * (LL * LL);

  for (int r = wid * 16; r < wid * 16 + 16; r++) {
    const float* srow = sbase + (size_t)(i0 + r) * LL + lane * 8;
    float4 a = *(const float4*)srow;
    float4 c = *(const float4*)(srow + 4);
    float m = fmaxf(fmaxf(fmaxf(a.x, a.y), fmaxf(a.z, a.w)),
                    fmaxf(fmaxf(c.x, c.y), fmaxf(c.z, c.w)));
#pragma unroll
    for (int off = 1; off < 64; off <<= 1) m = fmaxf(m, __shfl_xor(m, off, 64));
    float s = expf(a.x - m) + expf(a.y - m) + expf(a.z - m) + expf(a.w - m) +
              expf(c.x - m) + expf(c.y - m) + expf(c.z - m) + expf(c.w - m);
#pragma unroll
    for (int off = 1; off < 64; off <<= 1) s += __shfl_xor(s, off, 64);
    if (lane == 0) { smax[r] = m; srs[r] = 1.0f / s; }
  }
  __syncthreads();

  float acc[4][4] = {};
  int tx = t & 15, ty = t >> 4;
  const float* vb = v + (size_t)bh * (LL * DHH);
  int c4 = (t & 15) * 4, r0 = t >> 4;

  for (int jt = 0; jt < 8; jt++) {
    int j0 = jt * 64;
#pragma unroll
    for (int rr = 0; rr < 4; rr++) {
      int r = r0 + rr * 16;
      float4 s4 = *(const float4*)(sbase + (size_t)(i0 + r) * LL + j0 + c4);
      float m = smax[r], rs = srs[r];
      Pt[c4 + 0][r] = expf(s4.x - m) * rs;
      Pt[c4 + 1][r] = expf(s4.y - m) * rs;
      Pt[c4 + 2][r] = expf(s4.z - m) * rs;
      Pt[c4 + 3][r] = expf(s4.w - m) * rs;
      float4 v4 = *(const float4*)(vb + (size_t)(j0 + r) * DHH + c4);
      *(float4*)&Vt[r][c4] = v4;
    }
    __syncthreads();
#pragma unroll 8
    for (int kk = 0; kk < 64; kk++) {
      float4 a4 = *(const float4*)&Pt[kk][ty * 4];
      float4 b4 = *(const float4*)&Vt[kk][tx * 4];
      float ar[4] = {a4.x, a4.y, a4.z, a4.w};
      float br[4] = {b4.x, b4.y, b4.z, b4.w};
#pragma unroll
      for (int i2 = 0; i2 < 4; i2++)
#pragma unroll
        for (int j2 = 0; j2 < 4; j2++)
          acc[i2][j2] += ar[i2] * br[j2];
    }
    __syncthreads();
  }

#pragma unroll
  for (int i2 = 0; i2 < 4; i2++) {
    int i = i0 + ty * 4 + i2;
    u32 lo = (u32)f2bf(acc[i2][0]) | ((u32)f2bf(acc[i2][1]) << 16);
    u32 hi = (u32)f2bf(acc[i2][2]) | ((u32)f2bf(acc[i2][3]) << 16);
    *(uint2*)&olbd[((size_t)i * BB + b) * DD + h * 64 + tx * 4] =
        make_uint2(lo, hi);
  }
}

// ---------------------------------------------------------------------------
extern "C" void kernel_launch(void* const* d_in, const int* in_sizes, int n_in,
                              void* d_out, int out_size, void* d_ws, size_t ws_size,
                              hipStream_t stream) {
  const float* x      = (const float*)d_in[0];
  const float* edge   = (const float*)d_in[1];
  const int*   bdist  = (const int*)d_in[2];
  const float* W_in   = (const float*)d_in[3];
  const float* b_in   = (const float*)d_in[4];
  const float* pe_emb = (const float*)d_in[5];
  const float* W_out  = (const float*)d_in[6];
  const float* b_out  = (const float*)d_in[7];
  const float* W1     = (const float*)d_in[8];
  const float* b1     = (const float*)d_in[9];
  const float* W2     = (const float*)d_in[10];
  const float* b2     = (const float*)d_in[11];
  const float* ln1w   = (const float*)d_in[12];
  const float* ln1b   = (const float*)d_in[13];
  const float* ln2w   = (const float*)d_in[14];
  const float* ln2b   = (const float*)d_in[15];

  float* xout = (float*)d_out;                 // [L,B,D]
  float* eout = xout + (size_t)LL * BB * DD;   // [B*H,L,L] == scores

  // Workspace layout (float units). Max offset used: 36,077,568 floats.
  float* ws    = (float*)d_ws;
  u16*   xnb   = (u16*)ws;                       // bf16 LN out, both LNs
  float* qkv   = ws + 3145728;                   // fp32 [4096,2304]
  u16*   olbdb = (u16*)(ws + 3145728);           // bf16 O (after qkv dead)
  float* x1    = ws + 6291456;                   // fp32 [4096,768]
  float* pe    = ws + 12582912;                  // fp32 [128,2304]
  float* q     = ws + 12877824;
  float* k     = ws + 16023552;
  float* vv    = ws + 19169280;
  float* kp    = ws + 22315008;                  // [96,512,128]
  float* qp    = ws + 28606464;                  // [96,512,128]
  u16*   ff1b  = (u16*)(ws + 22315008);          // bf16 [4096,3072] (kp dead)
  u16*   W1b   = (u16*)(ws + 28606464);          // (qp region, after gather)
  u16*   W2b   = (u16*)(ws + 29786112);
  u16*   W_inb = (u16*)(ws + 34897920);
  u16*   W_outb= (u16*)(ws + 35782656);

  // 0) weight conversions needed before step 2 / 11
  f2b_kernel<<<1728, 256, 0, stream>>>(W_in, W_inb);    // 1,769,472
  f2b_kernel<<<576, 256, 0, stream>>>(W_out, W_outb);   //   589,824
  // 1) LN1 -> bf16
  ln_bf16<<<4096, 256, 0, stream>>>(x, ln1w, ln1b, xnb);
  // 2) qkv = xn @ W_in^T + b_in  (MFMA, fp32 out)
  gemm_mfma<0, 0, 0><<<dim3(18, 32), 256, 0, stream>>>(
      xnb, DD, W_inb, DD, qkv, 3 * DD, b_in, nullptr, DD);
  // 3) pe_proj = pe_emb @ W_in^T + b_in (fp32)
  gemm_kernel<<<dim3(36, 2, 1), 256, 0, stream>>>(
      pe_emb, DD, 0, 0, W_in, DD, 0, 0, pe, 3 * DD, 0, 0, b_in, nullptr, DD, 0);
  // 4) split to q,k,v
  split_qkv<<<12288, 256, 0, stream>>>(qkv, q, k, vv);
  // 5) t = q k^T per head -> eout
  gemm_kernel<<<dim3(8, 8, 96), 256, 0, stream>>>(
      q, DHH, (long)HH * LL * DHH, (long)LL * DHH,
      k, DHH, (long)HH * LL * DHH, (long)LL * DHH,
      eout, LL, (long)HH * LL * LL, (long)LL * LL, nullptr, nullptr, DHH, 0);
  // 6) kp = k @ pe_q^T
  gemm_kernel<<<dim3(2, 8, 96), 256, 0, stream>>>(
      k, DHH, (long)HH * LL * DHH, (long)LL * DHH,
      pe, 3 * DD, 0, 64,
      kp, PP, (long)HH * LL * PP, (long)LL * PP, nullptr, nullptr, DHH, 0);
  // 7) qp = q @ pe_k^T
  gemm_kernel<<<dim3(2, 8, 96), 256, 0, stream>>>(
      q, DHH, (long)HH * LL * DHH, (long)LL * DHH,
      pe + DD, 3 * DD, 0, 64,
      qp, PP, (long)HH * LL * PP, (long)LL * PP, nullptr, nullptr, DHH, 0);
  // 8) eout = (t + gathers)*inv + edge
  gather_scale<<<4096, 256, 0, stream>>>(kp, qp, bdist, edge, eout);
  // 8.5) W1/W2 conversions (qp region now dead)
  f2b_kernel<<<2304, 256, 0, stream>>>(W1, W1b);        // 2,359,296
  f2b_kernel<<<2304, 256, 0, stream>>>(W2, W2b);
  // 9) fused softmax + PV -> olbd bf16 [L,B,D]
  softmax_pv_tiled<<<dim3(8, 96), 256, 0, stream>>>(eout, vv, olbdb);
  // 11) x1 = O @ W_out^T + b_out + x   (MFMA)
  gemm_mfma<0, 0, 1><<<dim3(6, 32), 256, 0, stream>>>(
      olbdb, DD, W_outb, DD, x1, DD, b_out, x, DD);
  // 12) LN2 -> bf16
  ln_bf16<<<4096, 256, 0, stream>>>(x1, ln2w, ln2b, xnb);
  // 13) ff1 = gelu(xn @ W1^T + b1)   (MFMA, bf16 out)
  gemm_mfma<1, 1, 0><<<dim3(24, 32), 256, 0, stream>>>(
      xnb, DD, W1b, DD, ff1b, 4 * DD, b1, nullptr, DD);
  // 14) x_out = ff1 @ W2^T + b2 + x1 (MFMA, K=3072)
  gemm_mfma<0, 0, 1><<<dim3(6, 32), 256, 0, stream>>>(
      ff1b, 4 * DD, W2b, 4 * DD, xout, DD, b2, x1, 4 * DD);
}

// Round 6
// 556.966 us; speedup vs baseline: 3.9068x; 1.0538x over previous
//
#include <hip/hip_runtime.h>
#include <hip/hip_bf16.h>
#include <math.h>

// Problem constants
#define LL 512
#define BB 8
#define DD 768
#define HH 12
#define DHH 64
#define PP 128

typedef unsigned char u8;
typedef unsigned short u16;
typedef unsigned int u32;
typedef __attribute__((ext_vector_type(8))) short bf16x8;
typedef __attribute__((ext_vector_type(4))) float f32x4;

__device__ __forceinline__ u16 f2bf(float f) {
  u32 u = __float_as_uint(f);
  u32 r = (u + 0x7fffu + ((u >> 16) & 1u)) >> 16;
  return (u16)r;
}
__device__ __forceinline__ float bf2f(u16 u) {
  return __uint_as_float((u32)u << 16);
}

#define GLDS(g, l)                                                             \
  __builtin_amdgcn_global_load_lds(                                            \
      (const __attribute__((address_space(1))) void*)(g),                      \
      (__attribute__((address_space(3))) void*)(l), 16, 0, 0)

// ---------------------------------------------------------------------------
__device__ __forceinline__ void block_reduce2(float& a, float& b, float* sbuf) {
#pragma unroll
  for (int off = 32; off > 0; off >>= 1) {
    a += __shfl_down(a, off, 64);
    b += __shfl_down(b, off, 64);
  }
  int wid = threadIdx.x >> 6, lane = threadIdx.x & 63;
  __syncthreads();
  if (lane == 0) { sbuf[wid] = a; sbuf[4 + wid] = b; }
  __syncthreads();
  a = sbuf[0] + sbuf[1] + sbuf[2] + sbuf[3];
  b = sbuf[4] + sbuf[5] + sbuf[6] + sbuf[7];
}

// LayerNorm over D=768, one block per row, bf16 output
__global__ __launch_bounds__(256) void ln_bf16(const float* __restrict__ x,
                                               const float* __restrict__ w,
                                               const float* __restrict__ bb,
                                               u16* __restrict__ out) {
  __shared__ float sbuf[8];
  size_t row = blockIdx.x;
  const float* xr = x + row * DD;
  int t = threadIdx.x;
  float v0 = xr[t], v1 = xr[t + 256], v2 = xr[t + 512];
  float s = v0 + v1 + v2;
  float ss = v0 * v0 + v1 * v1 + v2 * v2;
  block_reduce2(s, ss, sbuf);
  float mu = s * (1.0f / DD);
  float var = ss * (1.0f / DD) - mu * mu;
  float r = rsqrtf(var + 1e-5f);
  u16* orow = out + row * DD;
  orow[t]       = f2bf((v0 - mu) * r * w[t]       + bb[t]);
  orow[t + 256] = f2bf((v1 - mu) * r * w[t + 256] + bb[t + 256]);
  orow[t + 512] = f2bf((v2 - mu) * r * w[t + 512] + bb[t + 512]);
}

// fp32 -> bf16, 4 elements/thread
__global__ __launch_bounds__(256) void f2b_kernel(const float* __restrict__ in,
                                                  u16* __restrict__ out) {
  int idx = blockIdx.x * 256 + threadIdx.x;
  float4 v = *(const float4*)(in + (size_t)idx * 4);
  u32 lo = (u32)f2bf(v.x) | ((u32)f2bf(v.y) << 16);
  u32 hi = (u32)f2bf(v.z) | ((u32)f2bf(v.w) << 16);
  *(uint2*)(out + (size_t)idx * 4) = make_uint2(lo, hi);
}

// bdist [L,L,B] int32 -> bdistT [B,L,L] u8 (values < 128)
__global__ __launch_bounds__(256) void bdist_t(const int* __restrict__ bd,
                                               u8* __restrict__ out) {
  int t = blockIdx.x * 256 + threadIdx.x;  // 2,097,152 items, read-coalesced
  int b = t & 7, jj = (t >> 3) & 511, ii = t >> 12;
  out[((size_t)b << 18) + ((size_t)ii << 9) + jj] = (u8)bd[t];
}

// ---------------------------------------------------------------------------
// bf16 MFMA GEMM (round-3-proven): C = act(A * B^T + bias) [+ residual].
// 128x128 tile, BK=32, 4 waves 2x2. Requires 128 | grid-covered M,N; 32 | K.
template <int ACT, int OBF, int RES>
__global__ __launch_bounds__(256) void gemm_mfma(
    const u16* __restrict__ A, int lda, const u16* __restrict__ B, int ldb,
    void* __restrict__ Cv, int ldc, const float* __restrict__ bias,
    const float* __restrict__ residual, int K) {
  __shared__ __align__(16) u16 Asl[128 * 32];
  __shared__ __align__(16) u16 Bsl[128 * 32];
  int t = threadIdx.x;
  int m0 = blockIdx.y * 128, n0 = blockIdx.x * 128;
  int lane = t & 63, w = t >> 6;
  int wr = w >> 1, wc = w & 1;
  int lr = lane & 15, lg = lane >> 4;

  f32x4 acc[4][4] = {};

  const u16* Ag0 = A + (size_t)(m0 + (t >> 2)) * lda + (t & 3) * 8;
  const u16* Ag1 = A + (size_t)(m0 + 64 + (t >> 2)) * lda + (t & 3) * 8;
  const u16* Bg0 = B + (size_t)(n0 + (t >> 2)) * ldb + (t & 3) * 8;
  const u16* Bg1 = B + (size_t)(n0 + 64 + (t >> 2)) * ldb + (t & 3) * 8;
  u16* Ad0 = &Asl[t * 8];
  u16* Ad1 = &Asl[2048 + t * 8];
  u16* Bd0 = &Bsl[t * 8];
  u16* Bd1 = &Bsl[2048 + t * 8];

  for (int k0 = 0; k0 < K; k0 += 32) {
    GLDS(Ag0 + k0, Ad0);
    GLDS(Ag1 + k0, Ad1);
    GLDS(Bg0 + k0, Bd0);
    GLDS(Bg1 + k0, Bd1);
    __syncthreads();
    bf16x8 a[4], b[4];
#pragma unroll
    for (int i = 0; i < 4; i++)
      a[i] = *(const bf16x8*)&Asl[(wr * 64 + i * 16 + lr) * 32 + lg * 8];
#pragma unroll
    for (int j = 0; j < 4; j++)
      b[j] = *(const bf16x8*)&Bsl[(wc * 64 + j * 16 + lr) * 32 + lg * 8];
#pragma unroll
    for (int i = 0; i < 4; i++)
#pragma unroll
      for (int j = 0; j < 4; j++)
        asm volatile("v_mfma_f32_16x16x32_bf16 %0, %1, %2, %0"
                     : "+v"(acc[i][j])
                     : "v"(a[i]), "v"(b[j]));
    __syncthreads();
  }
  asm volatile("s_nop 7\n\ts_nop 7" ::);

  float* Cf = (float*)Cv;
  u16* Cb = (u16*)Cv;
#pragma unroll
  for (int i = 0; i < 4; i++) {
#pragma unroll
    for (int r = 0; r < 4; r++) {
      int row = m0 + wr * 64 + i * 16 + lg * 4 + r;
#pragma unroll
      for (int j = 0; j < 4; j++) {
        int col = n0 + wc * 64 + j * 16 + lr;
        float vv = acc[i][j][r];
        if (bias) vv += bias[col];
        if (ACT) vv = 0.5f * vv * (1.0f + erff(vv * 0.70710678118654752f));
        if (RES) vv += residual[(size_t)row * ldc + col];
        if (OBF) Cb[(size_t)row * ldc + col] = f2bf(vv);
        else     Cf[(size_t)row * ldc + col] = vv;
      }
    }
  }
}

// ---------------------------------------------------------------------------
// Generic fp32 GEMM (round-3-proven): C = A*B^T (+bias).
template <int OBF>
__global__ __launch_bounds__(256) void gemm_kernel(
    const float* __restrict__ A, int lda, long sAo, long sAi,
    const float* __restrict__ B, int ldb, long sBo, long sBi,
    void* __restrict__ Cv, int ldc, long sCo, long sCi,
    const float* __restrict__ bias,
    const float* __restrict__ residual,
    int K, int act) {
  int z = blockIdx.z;
  int zo = z / HH, zi = z - zo * HH;
  A += (size_t)zo * sAo + (size_t)zi * sAi;
  B += (size_t)zo * sBo + (size_t)zi * sBi;
  size_t coff = (size_t)zo * sCo + (size_t)zi * sCi;

  __shared__ float As[16][68];
  __shared__ float Bs[16][68];
  int tid = threadIdx.x;
  int tx = tid & 15, ty = tid >> 4;
  int m0 = blockIdx.y * 64, n0 = blockIdx.x * 64;
  float acc[4][4] = {};
  int r = tid >> 2, kq = (tid & 3) * 4;

  for (int k0 = 0; k0 < K; k0 += 16) {
    float4 av = *(const float4*)(A + (size_t)(m0 + r) * lda + (k0 + kq));
    float4 bv = *(const float4*)(B + (size_t)(n0 + r) * ldb + (k0 + kq));
    As[kq + 0][r] = av.x; As[kq + 1][r] = av.y; As[kq + 2][r] = av.z; As[kq + 3][r] = av.w;
    Bs[kq + 0][r] = bv.x; Bs[kq + 1][r] = bv.y; Bs[kq + 2][r] = bv.z; Bs[kq + 3][r] = bv.w;
    __syncthreads();
#pragma unroll
    for (int kk = 0; kk < 16; kk++) {
      float4 a4 = *(const float4*)&As[kk][ty * 4];
      float4 b4 = *(const float4*)&Bs[kk][tx * 4];
      float ar[4] = {a4.x, a4.y, a4.z, a4.w};
      float br[4] = {b4.x, b4.y, b4.z, b4.w};
#pragma unroll
      for (int i2 = 0; i2 < 4; i2++)
#pragma unroll
        for (int j2 = 0; j2 < 4; j2++)
          acc[i2][j2] += ar[i2] * br[j2];
    }
    __syncthreads();
  }

  float bs[4] = {0.f, 0.f, 0.f, 0.f};
  if (bias) {
    float4 b4 = *(const float4*)&bias[n0 + tx * 4];
    bs[0] = b4.x; bs[1] = b4.y; bs[2] = b4.z; bs[3] = b4.w;
  }
  float* Cf = (float*)Cv;
  u16* Cb = (u16*)Cv;
#pragma unroll
  for (int i2 = 0; i2 < 4; i2++) {
    size_t m = (size_t)(m0 + ty * 4 + i2);
    float vout[4];
#pragma unroll
    for (int j2 = 0; j2 < 4; j2++) vout[j2] = acc[i2][j2] + bs[j2];
    if (residual) {
      const float4 r4 = *(const float4*)&residual[coff + m * ldc + n0 + tx * 4];
      vout[0] += r4.x; vout[1] += r4.y; vout[2] += r4.z; vout[3] += r4.w;
    }
    if (OBF) {
      u32 lo = (u32)f2bf(vout[0]) | ((u32)f2bf(vout[1]) << 16);
      u32 hi = (u32)f2bf(vout[2]) | ((u32)f2bf(vout[3]) << 16);
      *(uint2*)&Cb[coff + m * ldc + n0 + tx * 4] = make_uint2(lo, hi);
    } else {
      *(float4*)&Cf[coff + m * ldc + n0 + tx * 4] =
          make_float4(vout[0], vout[1], vout[2], vout[3]);
    }
  }
}

// ---------------------------------------------------------------------------
// qkv fp32 [L*B, 3D] -> q,k fp32 [B,H,L,Dh] + vb bf16 [B,H,L,Dh]
__global__ __launch_bounds__(256) void split_qkv3(const float* __restrict__ qkv,
                                                  float* __restrict__ q,
                                                  float* __restrict__ k,
                                                  u16* __restrict__ vb) {
  int idx = blockIdx.x * 256 + threadIdx.x;  // over 3,145,728
  int d = idx & 63;
  int l = (idx >> 6) & 511;
  int bh = idx >> 15;
  int b = bh / HH, h = bh - b * HH;
  size_t src = ((size_t)(l * BB + b)) * (3 * DD) + h * 64 + d;
  q[idx] = qkv[src];
  k[idx] = qkv[src + DD];
  vb[idx] = f2bf(qkv[src + 2 * DD]);
}

// ---------------------------------------------------------------------------
// Fused fp32 QK^T (round-3-proven tile math) + bdist gathers + scale + edge
// -> final scores, plus per-(row, 64-col-tile) softmax partials -> stats.
// Grid (8, 8, 96): one block per (bh, 64-row, 64-col) tile. stats[.,row][16]:
// [0..7] = tile max, [8..15] = tile expsum.
__global__ __launch_bounds__(256) void qkt_gather_f32(
    const float* __restrict__ q, const float* __restrict__ k,
    const float* __restrict__ kp, const float* __restrict__ qp,
    const u8* __restrict__ bdT, const float* __restrict__ edge,
    float* __restrict__ eout, float* __restrict__ stats) {
  int bh = blockIdx.z, b = bh / HH;
  int i0 = blockIdx.y * 64, j0 = blockIdx.x * 64, jt = blockIdx.x;
  __shared__ float As[16][68];
  __shared__ float Bs[16][68];
  int tid = threadIdx.x;
  int tx = tid & 15, ty = tid >> 4;
  float acc[4][4] = {};
  int r = tid >> 2, kq = (tid & 3) * 4;
  const float* A = q + (size_t)bh * (LL * DHH);
  const float* B = k + (size_t)bh * (LL * DHH);

  for (int k0 = 0; k0 < DHH; k0 += 16) {
    float4 av = *(const float4*)(A + (size_t)(i0 + r) * DHH + (k0 + kq));
    float4 bv = *(const float4*)(B + (size_t)(j0 + r) * DHH + (k0 + kq));
    As[kq + 0][r] = av.x; As[kq + 1][r] = av.y; As[kq + 2][r] = av.z; As[kq + 3][r] = av.w;
    Bs[kq + 0][r] = bv.x; Bs[kq + 1][r] = bv.y; Bs[kq + 2][r] = bv.z; Bs[kq + 3][r] = bv.w;
    __syncthreads();
#pragma unroll
    for (int kk = 0; kk < 16; kk++) {
      float4 a4 = *(const float4*)&As[kk][ty * 4];
      float4 b4 = *(const float4*)&Bs[kk][tx * 4];
      float ar[4] = {a4.x, a4.y, a4.z, a4.w};
      float br[4] = {b4.x, b4.y, b4.z, b4.w};
#pragma unroll
      for (int i2 = 0; i2 < 4; i2++)
#pragma unroll
        for (int j2 = 0; j2 < 4; j2++)
          acc[i2][j2] += ar[i2] * br[j2];
    }
    __syncthreads();
  }

  const u8* bd = bdT + (size_t)b * (LL * LL);
  const float* kpb = kp + (size_t)bh * (LL * PP);
  const float* qpb = qp + (size_t)bh * (LL * PP);
  const float* eb = edge + (size_t)bh * (LL * LL);
  float* ob = eout + (size_t)bh * (LL * LL);

  float rowm[4], rows[4];
#pragma unroll
  for (int i2 = 0; i2 < 4; i2++) {
    int row = i0 + ty * 4 + i2;
    int col0 = j0 + tx * 4;
    uchar4 p4 = *(const uchar4*)&bd[(size_t)row * LL + col0];
    float4 e4 = *(const float4*)&eb[(size_t)row * LL + col0];
    int pp[4] = {p4.x, p4.y, p4.z, p4.w};
    float ee[4] = {e4.x, e4.y, e4.z, e4.w};
    float sv[4];
#pragma unroll
    for (int j2 = 0; j2 < 4; j2++) {
      float gk = kpb[(col0 + j2) * PP + pp[j2]];
      float gq = qpb[row * PP + pp[j2]];
      sv[j2] = (acc[i2][j2] + gk + gq) * 0.125f + ee[j2];
    }
    *(float4*)&ob[(size_t)row * LL + col0] =
        make_float4(sv[0], sv[1], sv[2], sv[3]);
    float m = fmaxf(fmaxf(sv[0], sv[1]), fmaxf(sv[2], sv[3]));
#pragma unroll
    for (int off = 1; off < 16; off <<= 1) m = fmaxf(m, __shfl_xor(m, off, 64));
    float ss = expf(sv[0] - m) + expf(sv[1] - m) + expf(sv[2] - m) + expf(sv[3] - m);
#pragma unroll
    for (int off = 1; off < 16; off <<= 1) ss += __shfl_xor(ss, off, 64);
    rowm[i2] = m;
    rows[i2] = ss;
  }
  if (tx == 0) {
#pragma unroll
    for (int i2 = 0; i2 < 4; i2++) {
      size_t si = ((size_t)bh * LL + i0 + ty * 4 + i2) * 16 + jt;
      stats[si] = rowm[i2];
      stats[si + 8] = rows[i2];
    }
  }
}

// ---------------------------------------------------------------------------
// Fused softmax + P@V using precomputed tile stats; V bf16; O bf16 [L,B,D].
__global__ __launch_bounds__(256) void softmax_pv_tiled(
    const float* __restrict__ scores, const u16* __restrict__ vb_,
    const float* __restrict__ stats, u16* __restrict__ olbd) {
  int bh = blockIdx.y;
  int i0 = blockIdx.x * 64;
  int b = bh / HH, h = bh - b * HH;
  __shared__ float Pt[64][66];
  __shared__ float Vt[64][72];
  __shared__ float smax[64], srs[64];
  int t = threadIdx.x;
  const float* sbase = scores + (size_t)bh * (LL * LL);

  if (t < 64) {
    size_t si = ((size_t)bh * LL + i0 + t) * 16;
    float m = stats[si];
#pragma unroll
    for (int j = 1; j < 8; j++) m = fmaxf(m, stats[si + j]);
    float s = 0.f;
#pragma unroll
    for (int j = 0; j < 8; j++) s += stats[si + 8 + j] * expf(stats[si + j] - m);
    smax[t] = m;
    srs[t] = 1.0f / s;
  }
  __syncthreads();

  float acc[4][4] = {};
  int tx = t & 15, ty = t >> 4;
  const u16* vb = vb_ + (size_t)bh * (LL * DHH);
  int c4 = (t & 15) * 4, r0 = t >> 4;

  for (int jt = 0; jt < 8; jt++) {
    int j0 = jt * 64;
#pragma unroll
    for (int rr = 0; rr < 4; rr++) {
      int r = r0 + rr * 16;
      float4 s4 = *(const float4*)(sbase + (size_t)(i0 + r) * LL + j0 + c4);
      float m = smax[r], rs = srs[r];
      Pt[c4 + 0][r] = expf(s4.x - m) * rs;
      Pt[c4 + 1][r] = expf(s4.y - m) * rs;
      Pt[c4 + 2][r] = expf(s4.z - m) * rs;
      Pt[c4 + 3][r] = expf(s4.w - m) * rs;
      uint2 v2 = *(const uint2*)(vb + (size_t)(j0 + r) * DHH + c4);
      Vt[r][c4 + 0] = bf2f((u16)(v2.x & 0xffff));
      Vt[r][c4 + 1] = bf2f((u16)(v2.x >> 16));
      Vt[r][c4 + 2] = bf2f((u16)(v2.y & 0xffff));
      Vt[r][c4 + 3] = bf2f((u16)(v2.y >> 16));
    }
    __syncthreads();
#pragma unroll 8
    for (int kk = 0; kk < 64; kk++) {
      float4 a4 = *(const float4*)&Pt[kk][ty * 4];
      float4 b4 = *(const float4*)&Vt[kk][tx * 4];
      float ar[4] = {a4.x, a4.y, a4.z, a4.w};
      float br[4] = {b4.x, b4.y, b4.z, b4.w};
#pragma unroll
      for (int i2 = 0; i2 < 4; i2++)
#pragma unroll
        for (int j2 = 0; j2 < 4; j2++)
          acc[i2][j2] += ar[i2] * br[j2];
    }
    __syncthreads();
  }

#pragma unroll
  for (int i2 = 0; i2 < 4; i2++) {
    int i = i0 + ty * 4 + i2;
    u32 lo = (u32)f2bf(acc[i2][0]) | ((u32)f2bf(acc[i2][1]) << 16);
    u32 hi = (u32)f2bf(acc[i2][2]) | ((u32)f2bf(acc[i2][3]) << 16);
    *(uint2*)&olbd[((size_t)i * BB + b) * DD + h * 64 + tx * 4] =
        make_uint2(lo, hi);
  }
}

// ---------------------------------------------------------------------------
extern "C" void kernel_launch(void* const* d_in, const int* in_sizes, int n_in,
                              void* d_out, int out_size, void* d_ws, size_t ws_size,
                              hipStream_t stream) {
  const float* x      = (const float*)d_in[0];
  const float* edge   = (const float*)d_in[1];
  const int*   bdist  = (const int*)d_in[2];
  const float* W_in   = (const float*)d_in[3];
  const float* b_in   = (const float*)d_in[4];
  const float* pe_emb = (const float*)d_in[5];
  const float* W_out  = (const float*)d_in[6];
  const float* b_out  = (const float*)d_in[7];
  const float* W1     = (const float*)d_in[8];
  const float* b1     = (const float*)d_in[9];
  const float* W2     = (const float*)d_in[10];
  const float* b2     = (const float*)d_in[11];
  const float* ln1w   = (const float*)d_in[12];
  const float* ln1b   = (const float*)d_in[13];
  const float* ln2w   = (const float*)d_in[14];
  const float* ln2b   = (const float*)d_in[15];

  float* xout = (float*)d_out;                 // [L,B,D]
  float* eout = xout + (size_t)LL * BB * DD;   // [B*H,L,L] == final scores

  // Workspace layout (float units). Max used: 37,800,000 floats = 151.2 MB.
  float* ws = (float*)d_ws;
  u16*   xnb    = (u16*)(ws + 0);          // [4096,768] bf16, ends 1,572,864
  float* qkv    = ws + 1600000;            // [4096,2304] fp32, ends 11,037,184
  u16*   olbdb  = (u16*)(ws + 1600000);    // bf16 O, reuse after split
  u16*   ff1b   = (u16*)(ws + 3200000);    // [4096,3072] bf16, ends 9,491,456
  float* x1     = ws + 11100000;           // ends 14,245,728
  float* pe     = ws + 14300000;           // [128,2304] fp32, ends 14,594,912
  float* q      = ws + 14600000;           // ends 17,745,728
  float* k      = ws + 17800000;           // ends 20,945,728
  u16*   vb     = (u16*)(ws + 21000000);   // ends 22,572,864
  float* stats  = ws + 22600000;           // [96,512,16], ends 23,386,432
  u8*    bdT    = (u8*)(ws + 23400000);    // [8,512,512] u8, ends 23,924,288
  float* kp     = ws + 24000000;           // [96,512,128] fp32, ends 30,291,456
  float* qp     = ws + 30300000;           // ends 36,591,456
  u16*   W1b    = (u16*)(ws + 24000000);   // reuse kp region after qkt
  u16*   W2b    = (u16*)(ws + 25200000);   // reuse kp region after qkt
  u16*   W_inb  = (u16*)(ws + 36600000);   // ends 37,484,736
  u16*   W_outb = (u16*)(ws + 37500000);   // ends 37,794,912

  // 0) dtype conversions + bdist transpose
  f2b_kernel<<<1728, 256, 0, stream>>>(W_in, W_inb);
  f2b_kernel<<<576, 256, 0, stream>>>(W_out, W_outb);
  bdist_t<<<8192, 256, 0, stream>>>(bdist, bdT);
  // 1) LN1 -> bf16
  ln_bf16<<<4096, 256, 0, stream>>>(x, ln1w, ln1b, xnb);
  // 2) qkv = xn @ W_in^T + b_in  (MFMA, fp32 out — round-3-proven)
  gemm_mfma<0, 0, 0><<<dim3(18, 32), 256, 0, stream>>>(
      xnb, DD, W_inb, DD, qkv, 3 * DD, b_in, nullptr, DD);
  // 3) pe_proj fp32 (round-3-proven)
  gemm_kernel<0><<<dim3(36, 2, 1), 256, 0, stream>>>(
      pe_emb, DD, 0, 0, W_in, DD, 0, 0, pe, 3 * DD, 0, 0, b_in, nullptr, DD, 0);
  // 4) split -> q,k fp32 + vb bf16
  split_qkv3<<<12288, 256, 0, stream>>>(qkv, q, k, vb);
  // 5) kp = k @ pe_q^T per head (round-3-proven, fp32)
  gemm_kernel<0><<<dim3(2, 8, 96), 256, 0, stream>>>(
      k, DHH, (long)HH * LL * DHH, (long)LL * DHH,
      pe, 3 * DD, 0, 64,
      kp, PP, (long)HH * LL * PP, (long)LL * PP, nullptr, nullptr, DHH, 0);
  // 6) qp = q @ pe_k^T per head
  gemm_kernel<0><<<dim3(2, 8, 96), 256, 0, stream>>>(
      q, DHH, (long)HH * LL * DHH, (long)LL * DHH,
      pe + DD, 3 * DD, 0, 64,
      qp, PP, (long)HH * LL * PP, (long)LL * PP, nullptr, nullptr, DHH, 0);
  // 7) fused fp32 QK^T + gathers + edge -> eout, + softmax tile stats
  qkt_gather_f32<<<dim3(8, 8, 96), 256, 0, stream>>>(q, k, kp, qp, bdT, edge,
                                                     eout, stats);
  // 7.5) W1/W2 conversions (kp region now dead)
  f2b_kernel<<<2304, 256, 0, stream>>>(W1, W1b);
  f2b_kernel<<<2304, 256, 0, stream>>>(W2, W2b);
  // 8) fused softmax + PV -> olbd bf16 [L,B,D]
  softmax_pv_tiled<<<dim3(8, 96), 256, 0, stream>>>(eout, vb, stats, olbdb);
  // 9) x1 = O @ W_out^T + b_out + x
  gemm_mfma<0, 0, 1><<<dim3(6, 32), 256, 0, stream>>>(
      olbdb, DD, W_outb, DD, x1, DD, b_out, x, DD);
  // 10) LN2 -> bf16
  ln_bf16<<<4096, 256, 0, stream>>>(x1, ln2w, ln2b, xnb);
  // 11) ff1 = gelu(xn @ W1^T + b1) (bf16 out)
  gemm_mfma<1, 1, 0><<<dim3(24, 32), 256, 0, stream>>>(
      xnb, DD, W1b, DD, ff1b, 4 * DD, b1, nullptr, DD);
  // 12) x_out = ff1 @ W2^T + b2 + x1  (K=3072)
  gemm_mfma<0, 0, 1><<<dim3(6, 32), 256, 0, stream>>>(
      ff1b, 4 * DD, W2b, 4 * DD, xout, DD, b2, x1, 4 * DD);
}

// Round 7
// 510.578 us; speedup vs baseline: 4.2617x; 1.0909x over previous
//
#include <hip/hip_runtime.h>
#include <hip/hip_bf16.h>
#include <math.h>

// Problem constants
#define LL 512
#define BB 8
#define DD 768
#define HH 12
#define DHH 64
#define PP 128

typedef unsigned char u8;
typedef unsigned short u16;
typedef unsigned int u32;
typedef __attribute__((ext_vector_type(8))) short bf16x8;
typedef __attribute__((ext_vector_type(4))) float f32x4;

__device__ __forceinline__ u16 f2bf(float f) {
  u32 u = __float_as_uint(f);
  u32 r = (u + 0x7fffu + ((u >> 16) & 1u)) >> 16;
  return (u16)r;
}
__device__ __forceinline__ float bf2f(u16 u) {
  return __uint_as_float((u32)u << 16);
}

#define GLDS(g, l)                                                             \
  __builtin_amdgcn_global_load_lds(                                            \
      (const __attribute__((address_space(1))) void*)(g),                      \
      (__attribute__((address_space(3))) void*)(l), 16, 0, 0)

// ---------------------------------------------------------------------------
__device__ __forceinline__ void block_reduce2(float& a, float& b, float* sbuf) {
#pragma unroll
  for (int off = 32; off > 0; off >>= 1) {
    a += __shfl_down(a, off, 64);
    b += __shfl_down(b, off, 64);
  }
  int wid = threadIdx.x >> 6, lane = threadIdx.x & 63;
  __syncthreads();
  if (lane == 0) { sbuf[wid] = a; sbuf[4 + wid] = b; }
  __syncthreads();
  a = sbuf[0] + sbuf[1] + sbuf[2] + sbuf[3];
  b = sbuf[4] + sbuf[5] + sbuf[6] + sbuf[7];
}

// LayerNorm over D=768, one block per row, bf16 output
__global__ __launch_bounds__(256) void ln_bf16(const float* __restrict__ x,
                                               const float* __restrict__ w,
                                               const float* __restrict__ bb,
                                               u16* __restrict__ out) {
  __shared__ float sbuf[8];
  size_t row = blockIdx.x;
  const float* xr = x + row * DD;
  int t = threadIdx.x;
  float v0 = xr[t], v1 = xr[t + 256], v2 = xr[t + 512];
  float s = v0 + v1 + v2;
  float ss = v0 * v0 + v1 * v1 + v2 * v2;
  block_reduce2(s, ss, sbuf);
  float mu = s * (1.0f / DD);
  float var = ss * (1.0f / DD) - mu * mu;
  float r = rsqrtf(var + 1e-5f);
  u16* orow = out + row * DD;
  orow[t]       = f2bf((v0 - mu) * r * w[t]       + bb[t]);
  orow[t + 256] = f2bf((v1 - mu) * r * w[t + 256] + bb[t + 256]);
  orow[t + 512] = f2bf((v2 - mu) * r * w[t + 512] + bb[t + 512]);
}

// fp32 -> bf16, 4 elements/thread
__global__ __launch_bounds__(256) void f2b_kernel(const float* __restrict__ in,
                                                  u16* __restrict__ out) {
  int idx = blockIdx.x * 256 + threadIdx.x;
  float4 v = *(const float4*)(in + (size_t)idx * 4);
  u32 lo = (u32)f2bf(v.x) | ((u32)f2bf(v.y) << 16);
  u32 hi = (u32)f2bf(v.z) | ((u32)f2bf(v.w) << 16);
  *(uint2*)(out + (size_t)idx * 4) = make_uint2(lo, hi);
}

// bdist [L,L,B] int32 -> bdistT [B,L,L] u8 (values < 128)
__global__ __launch_bounds__(256) void bdist_t(const int* __restrict__ bd,
                                               u8* __restrict__ out) {
  int t = blockIdx.x * 256 + threadIdx.x;  // 2,097,152 items, read-coalesced
  int b = t & 7, jj = (t >> 3) & 511, ii = t >> 12;
  out[((size_t)b << 18) + ((size_t)ii << 9) + jj] = (u8)bd[t];
}

// ---------------------------------------------------------------------------
// bf16 MFMA GEMM (round-3-proven): C = act(A * B^T + bias) [+ residual].
// 128x128 tile, BK=32, 4 waves 2x2. Requires 128 | grid-covered M,N; 32 | K.
template <int ACT, int OBF, int RES>
__global__ __launch_bounds__(256) void gemm_mfma(
    const u16* __restrict__ A, int lda, const u16* __restrict__ B, int ldb,
    void* __restrict__ Cv, int ldc, const float* __restrict__ bias,
    const float* __restrict__ residual, int K) {
  __shared__ __align__(16) u16 Asl[128 * 32];
  __shared__ __align__(16) u16 Bsl[128 * 32];
  int t = threadIdx.x;
  int m0 = blockIdx.y * 128, n0 = blockIdx.x * 128;
  int lane = t & 63, w = t >> 6;
  int wr = w >> 1, wc = w & 1;
  int lr = lane & 15, lg = lane >> 4;

  f32x4 acc[4][4] = {};

  const u16* Ag0 = A + (size_t)(m0 + (t >> 2)) * lda + (t & 3) * 8;
  const u16* Ag1 = A + (size_t)(m0 + 64 + (t >> 2)) * lda + (t & 3) * 8;
  const u16* Bg0 = B + (size_t)(n0 + (t >> 2)) * ldb + (t & 3) * 8;
  const u16* Bg1 = B + (size_t)(n0 + 64 + (t >> 2)) * ldb + (t & 3) * 8;
  u16* Ad0 = &Asl[t * 8];
  u16* Ad1 = &Asl[2048 + t * 8];
  u16* Bd0 = &Bsl[t * 8];
  u16* Bd1 = &Bsl[2048 + t * 8];

  for (int k0 = 0; k0 < K; k0 += 32) {
    GLDS(Ag0 + k0, Ad0);
    GLDS(Ag1 + k0, Ad1);
    GLDS(Bg0 + k0, Bd0);
    GLDS(Bg1 + k0, Bd1);
    __syncthreads();
    bf16x8 a[4], b[4];
#pragma unroll
    for (int i = 0; i < 4; i++)
      a[i] = *(const bf16x8*)&Asl[(wr * 64 + i * 16 + lr) * 32 + lg * 8];
#pragma unroll
    for (int j = 0; j < 4; j++)
      b[j] = *(const bf16x8*)&Bsl[(wc * 64 + j * 16 + lr) * 32 + lg * 8];
#pragma unroll
    for (int i = 0; i < 4; i++)
#pragma unroll
      for (int j = 0; j < 4; j++)
        asm volatile("v_mfma_f32_16x16x32_bf16 %0, %1, %2, %0"
                     : "+v"(acc[i][j])
                     : "v"(a[i]), "v"(b[j]));
    __syncthreads();
  }
  asm volatile("s_nop 7\n\ts_nop 7" ::);

  float* Cf = (float*)Cv;
  u16* Cb = (u16*)Cv;
#pragma unroll
  for (int i = 0; i < 4; i++) {
#pragma unroll
    for (int r = 0; r < 4; r++) {
      int row = m0 + wr * 64 + i * 16 + lg * 4 + r;
#pragma unroll
      for (int j = 0; j < 4; j++) {
        int col = n0 + wc * 64 + j * 16 + lr;
        float vv = acc[i][j][r];
        if (bias) vv += bias[col];
        if (ACT) vv = 0.5f * vv * (1.0f + erff(vv * 0.70710678118654752f));
        if (RES) vv += residual[(size_t)row * ldc + col];
        if (OBF) Cb[(size_t)row * ldc + col] = f2bf(vv);
        else     Cf[(size_t)row * ldc + col] = vv;
      }
    }
  }
}

// ---------------------------------------------------------------------------
// Generic fp32 GEMM (round-3-proven): C = A*B^T (+bias); OBF=1 -> bf16 store.
template <int OBF>
__global__ __launch_bounds__(256) void gemm_kernel(
    const float* __restrict__ A, int lda, long sAo, long sAi,
    const float* __restrict__ B, int ldb, long sBo, long sBi,
    void* __restrict__ Cv, int ldc, long sCo, long sCi,
    const float* __restrict__ bias,
    const float* __restrict__ residual,
    int K, int act) {
  int z = blockIdx.z;
  int zo = z / HH, zi = z - zo * HH;
  A += (size_t)zo * sAo + (size_t)zi * sAi;
  B += (size_t)zo * sBo + (size_t)zi * sBi;
  size_t coff = (size_t)zo * sCo + (size_t)zi * sCi;

  __shared__ float As[16][68];
  __shared__ float Bs[16][68];
  int tid = threadIdx.x;
  int tx = tid & 15, ty = tid >> 4;
  int m0 = blockIdx.y * 64, n0 = blockIdx.x * 64;
  float acc[4][4] = {};
  int r = tid >> 2, kq = (tid & 3) * 4;

  for (int k0 = 0; k0 < K; k0 += 16) {
    float4 av = *(const float4*)(A + (size_t)(m0 + r) * lda + (k0 + kq));
    float4 bv = *(const float4*)(B + (size_t)(n0 + r) * ldb + (k0 + kq));
    As[kq + 0][r] = av.x; As[kq + 1][r] = av.y; As[kq + 2][r] = av.z; As[kq + 3][r] = av.w;
    Bs[kq + 0][r] = bv.x; Bs[kq + 1][r] = bv.y; Bs[kq + 2][r] = bv.z; Bs[kq + 3][r] = bv.w;
    __syncthreads();
#pragma unroll
    for (int kk = 0; kk < 16; kk++) {
      float4 a4 = *(const float4*)&As[kk][ty * 4];
      float4 b4 = *(const float4*)&Bs[kk][tx * 4];
      float ar[4] = {a4.x, a4.y, a4.z, a4.w};
      float br[4] = {b4.x, b4.y, b4.z, b4.w};
#pragma unroll
      for (int i2 = 0; i2 < 4; i2++)
#pragma unroll
        for (int j2 = 0; j2 < 4; j2++)
          acc[i2][j2] += ar[i2] * br[j2];
    }
    __syncthreads();
  }

  float bs[4] = {0.f, 0.f, 0.f, 0.f};
  if (bias) {
    float4 b4 = *(const float4*)&bias[n0 + tx * 4];
    bs[0] = b4.x; bs[1] = b4.y; bs[2] = b4.z; bs[3] = b4.w;
  }
  float* Cf = (float*)Cv;
  u16* Cb = (u16*)Cv;
#pragma unroll
  for (int i2 = 0; i2 < 4; i2++) {
    size_t m = (size_t)(m0 + ty * 4 + i2);
    float vout[4];
#pragma unroll
    for (int j2 = 0; j2 < 4; j2++) vout[j2] = acc[i2][j2] + bs[j2];
    if (residual) {
      const float4 r4 = *(const float4*)&residual[coff + m * ldc + n0 + tx * 4];
      vout[0] += r4.x; vout[1] += r4.y; vout[2] += r4.z; vout[3] += r4.w;
    }
    if (OBF) {
      u32 lo = (u32)f2bf(vout[0]) | ((u32)f2bf(vout[1]) << 16);
      u32 hi = (u32)f2bf(vout[2]) | ((u32)f2bf(vout[3]) << 16);
      *(uint2*)&Cb[coff + m * ldc + n0 + tx * 4] = make_uint2(lo, hi);
    } else {
      *(float4*)&Cf[coff + m * ldc + n0 + tx * 4] =
          make_float4(vout[0], vout[1], vout[2], vout[3]);
    }
  }
}

// ---------------------------------------------------------------------------
// qkv fp32 [L*B, 3D] -> q,k fp32 [B,H,L,Dh] + vb bf16 [B,H,L,Dh]
__global__ __launch_bounds__(256) void split_qkv3(const float* __restrict__ qkv,
                                                  float* __restrict__ q,
                                                  float* __restrict__ k,
                                                  u16* __restrict__ vb) {
  int idx = blockIdx.x * 256 + threadIdx.x;  // over 3,145,728
  int d = idx & 63;
  int l = (idx >> 6) & 511;
  int bh = idx >> 15;
  int b = bh / HH, h = bh - b * HH;
  size_t src = ((size_t)(l * BB + b)) * (3 * DD) + h * 64 + d;
  q[idx] = qkv[src];
  k[idx] = qkv[src + DD];
  vb[idx] = f2bf(qkv[src + 2 * DD]);
}

// ---------------------------------------------------------------------------
// Fused fp32 QK^T + LDS-staged bf16 kp/qp gathers + scale + edge -> scores,
// plus per-(row, 64-col-tile) softmax partials -> stats.
// Grid (8, 8, 96). stats[.,row][16]: [0..7] = tile max, [8..15] = tile expsum.
__global__ __launch_bounds__(256) void qkt_gather_f32(
    const float* __restrict__ q, const float* __restrict__ k,
    const u16* __restrict__ kp, const u16* __restrict__ qp,
    const u8* __restrict__ bdT, const float* __restrict__ edge,
    float* __restrict__ eout, float* __restrict__ stats) {
  int bh = blockIdx.z, b = bh / HH;
  int i0 = blockIdx.y * 64, j0 = blockIdx.x * 64, jt = blockIdx.x;
  __shared__ float As[16][68];
  __shared__ float Bs[16][68];
  __shared__ u16 kpl[64][PP];   // kp rows j0..j0+63 (gather by output col)
  __shared__ u16 qpl[64][PP];   // qp rows i0..i0+63 (gather by output row)
  int tid = threadIdx.x;
  int tx = tid & 15, ty = tid >> 4;

  // Stage gather tables (coalesced uint4 = 8 bf16), 4 chunks/thread each.
  const u16* kpg = kp + (size_t)bh * (LL * PP);
  const u16* qpg = qp + (size_t)bh * (LL * PP);
  for (int c = tid; c < 1024; c += 256) {
    int row = c >> 4, ch = (c & 15) * 8;
    *(uint4*)&kpl[row][ch] = *(const uint4*)&kpg[(size_t)(j0 + row) * PP + ch];
    *(uint4*)&qpl[row][ch] = *(const uint4*)&qpg[(size_t)(i0 + row) * PP + ch];
  }

  float acc[4][4] = {};
  int r = tid >> 2, kq = (tid & 3) * 4;
  const float* A = q + (size_t)bh * (LL * DHH);
  const float* B = k + (size_t)bh * (LL * DHH);

  for (int k0 = 0; k0 < DHH; k0 += 16) {
    float4 av = *(const float4*)(A + (size_t)(i0 + r) * DHH + (k0 + kq));
    float4 bv = *(const float4*)(B + (size_t)(j0 + r) * DHH + (k0 + kq));
    As[kq + 0][r] = av.x; As[kq + 1][r] = av.y; As[kq + 2][r] = av.z; As[kq + 3][r] = av.w;
    Bs[kq + 0][r] = bv.x; Bs[kq + 1][r] = bv.y; Bs[kq + 2][r] = bv.z; Bs[kq + 3][r] = bv.w;
    __syncthreads();
#pragma unroll
    for (int kk = 0; kk < 16; kk++) {
      float4 a4 = *(const float4*)&As[kk][ty * 4];
      float4 b4 = *(const float4*)&Bs[kk][tx * 4];
      float ar[4] = {a4.x, a4.y, a4.z, a4.w};
      float br[4] = {b4.x, b4.y, b4.z, b4.w};
#pragma unroll
      for (int i2 = 0; i2 < 4; i2++)
#pragma unroll
        for (int j2 = 0; j2 < 4; j2++)
          acc[i2][j2] += ar[i2] * br[j2];
    }
    __syncthreads();
  }

  const u8* bd = bdT + (size_t)b * (LL * LL);
  const float* eb = edge + (size_t)bh * (LL * LL);
  float* ob = eout + (size_t)bh * (LL * LL);

  float rowm[4], rows[4];
#pragma unroll
  for (int i2 = 0; i2 < 4; i2++) {
    int row = i0 + ty * 4 + i2;
    int col0 = j0 + tx * 4;
    uchar4 p4 = *(const uchar4*)&bd[(size_t)row * LL + col0];
    float4 e4 = *(const float4*)&eb[(size_t)row * LL + col0];
    int pp[4] = {p4.x, p4.y, p4.z, p4.w};
    float ee[4] = {e4.x, e4.y, e4.z, e4.w};
    float sv[4];
#pragma unroll
    for (int j2 = 0; j2 < 4; j2++) {
      float gk = bf2f(kpl[tx * 4 + j2][pp[j2]]);
      float gq = bf2f(qpl[ty * 4 + i2][pp[j2]]);
      sv[j2] = (acc[i2][j2] + gk + gq) * 0.125f + ee[j2];
    }
    *(float4*)&ob[(size_t)row * LL + col0] =
        make_float4(sv[0], sv[1], sv[2], sv[3]);
    float m = fmaxf(fmaxf(sv[0], sv[1]), fmaxf(sv[2], sv[3]));
#pragma unroll
    for (int off = 1; off < 16; off <<= 1) m = fmaxf(m, __shfl_xor(m, off, 64));
    float ss = expf(sv[0] - m) + expf(sv[1] - m) + expf(sv[2] - m) + expf(sv[3] - m);
#pragma unroll
    for (int off = 1; off < 16; off <<= 1) ss += __shfl_xor(ss, off, 64);
    rowm[i2] = m;
    rows[i2] = ss;
  }
  if (tx == 0) {
#pragma unroll
    for (int i2 = 0; i2 < 4; i2++) {
      size_t si = ((size_t)bh * LL + i0 + ty * 4 + i2) * 16 + jt;
      stats[si] = rowm[i2];
      stats[si + 8] = rows[i2];
    }
  }
}

// ---------------------------------------------------------------------------
// Fused softmax + P@V using precomputed tile stats; V bf16; O bf16 [L,B,D].
__global__ __launch_bounds__(256) void softmax_pv_tiled(
    const float* __restrict__ scores, const u16* __restrict__ vb_,
    const float* __restrict__ stats, u16* __restrict__ olbd) {
  int bh = blockIdx.y;
  int i0 = blockIdx.x * 64;
  int b = bh / HH, h = bh - b * HH;
  __shared__ float Pt[64][66];
  __shared__ float Vt[64][72];
  __shared__ float smax[64], srs[64];
  int t = threadIdx.x;
  const float* sbase = scores + (size_t)bh * (LL * LL);

  if (t < 64) {
    size_t si = ((size_t)bh * LL + i0 + t) * 16;
    float m = stats[si];
#pragma unroll
    for (int j = 1; j < 8; j++) m = fmaxf(m, stats[si + j]);
    float s = 0.f;
#pragma unroll
    for (int j = 0; j < 8; j++) s += stats[si + 8 + j] * expf(stats[si + j] - m);
    smax[t] = m;
    srs[t] = 1.0f / s;
  }
  __syncthreads();

  float acc[4][4] = {};
  int tx = t & 15, ty = t >> 4;
  const u16* vb = vb_ + (size_t)bh * (LL * DHH);
  int c4 = (t & 15) * 4, r0 = t >> 4;

  for (int jt = 0; jt < 8; jt++) {
    int j0 = jt * 64;
#pragma unroll
    for (int rr = 0; rr < 4; rr++) {
      int r = r0 + rr * 16;
      float4 s4 = *(const float4*)(sbase + (size_t)(i0 + r) * LL + j0 + c4);
      float m = smax[r], rs = srs[r];
      Pt[c4 + 0][r] = expf(s4.x - m) * rs;
      Pt[c4 + 1][r] = expf(s4.y - m) * rs;
      Pt[c4 + 2][r] = expf(s4.z - m) * rs;
      Pt[c4 + 3][r] = expf(s4.w - m) * rs;
      uint2 v2 = *(const uint2*)(vb + (size_t)(j0 + r) * DHH + c4);
      Vt[r][c4 + 0] = bf2f((u16)(v2.x & 0xffff));
      Vt[r][c4 + 1] = bf2f((u16)(v2.x >> 16));
      Vt[r][c4 + 2] = bf2f((u16)(v2.y & 0xffff));
      Vt[r][c4 + 3] = bf2f((u16)(v2.y >> 16));
    }
    __syncthreads();
#pragma unroll 8
    for (int kk = 0; kk < 64; kk++) {
      float4 a4 = *(const float4*)&Pt[kk][ty * 4];
      float4 b4 = *(const float4*)&Vt[kk][tx * 4];
      float ar[4] = {a4.x, a4.y, a4.z, a4.w};
      float br[4] = {b4.x, b4.y, b4.z, b4.w};
#pragma unroll
      for (int i2 = 0; i2 < 4; i2++)
#pragma unroll
        for (int j2 = 0; j2 < 4; j2++)
          acc[i2][j2] += ar[i2] * br[j2];
    }
    __syncthreads();
  }

#pragma unroll
  for (int i2 = 0; i2 < 4; i2++) {
    int i = i0 + ty * 4 + i2;
    u32 lo = (u32)f2bf(acc[i2][0]) | ((u32)f2bf(acc[i2][1]) << 16);
    u32 hi = (u32)f2bf(acc[i2][2]) | ((u32)f2bf(acc[i2][3]) << 16);
    *(uint2*)&olbd[((size_t)i * BB + b) * DD + h * 64 + tx * 4] =
        make_uint2(lo, hi);
  }
}

// ---------------------------------------------------------------------------
extern "C" void kernel_launch(void* const* d_in, const int* in_sizes, int n_in,
                              void* d_out, int out_size, void* d_ws, size_t ws_size,
                              hipStream_t stream) {
  const float* x      = (const float*)d_in[0];
  const float* edge   = (const float*)d_in[1];
  const int*   bdist  = (const int*)d_in[2];
  const float* W_in   = (const float*)d_in[3];
  const float* b_in   = (const float*)d_in[4];
  const float* pe_emb = (const float*)d_in[5];
  const float* W_out  = (const float*)d_in[6];
  const float* b_out  = (const float*)d_in[7];
  const float* W1     = (const float*)d_in[8];
  const float* b1     = (const float*)d_in[9];
  const float* W2     = (const float*)d_in[10];
  const float* b2     = (const float*)d_in[11];
  const float* ln1w   = (const float*)d_in[12];
  const float* ln1b   = (const float*)d_in[13];
  const float* ln2w   = (const float*)d_in[14];
  const float* ln2b   = (const float*)d_in[15];

  float* xout = (float*)d_out;                 // [L,B,D]
  float* eout = xout + (size_t)LL * BB * DD;   // [B*H,L,L] == final scores

  // Workspace layout (float units). Max used: ~34,000,000 floats = 136 MB.
  float* ws = (float*)d_ws;
  u16*   xnb    = (u16*)(ws + 0);          // [4096,768] bf16, ends 786,432
  float* qkv    = ws + 1600000;            // [4096,2304] fp32, ends 11,037,184
  u16*   olbdb  = (u16*)(ws + 1600000);    // bf16 O, reuse after split
  u16*   ff1b   = (u16*)(ws + 3200000);    // [4096,3072] bf16, ends 9,491,456
  float* x1     = ws + 11100000;           // ends 14,245,728
  float* pe     = ws + 14300000;           // [128,2304] fp32, ends 14,594,912
  float* q      = ws + 14600000;           // ends 17,745,728
  float* k      = ws + 17800000;           // ends 20,945,728
  u16*   vb     = (u16*)(ws + 21000000);   // ends 22,572,864
  float* stats  = ws + 22600000;           // [96,512,16], ends 23,386,432
  u8*    bdT    = (u8*)(ws + 23400000);    // [8,512,512] u8, ends 23,924,288
  u16*   kpb    = (u16*)(ws + 24000000);   // [96,512,128] bf16, ends 27,145,728
  u16*   qpb    = (u16*)(ws + 27200000);   // ends 30,345,728
  u16*   W1b    = (u16*)(ws + 30400000);   // ends 31,579,648
  u16*   W2b    = (u16*)(ws + 31600000);   // ends 32,779,648
  u16*   W_inb  = (u16*)(ws + 32800000);   // ends 33,684,736
  u16*   W_outb = (u16*)(ws + 33700000);   // ends 33,994,912

  // 0) dtype conversions + bdist transpose
  f2b_kernel<<<1728, 256, 0, stream>>>(W_in, W_inb);
  f2b_kernel<<<576, 256, 0, stream>>>(W_out, W_outb);
  f2b_kernel<<<2304, 256, 0, stream>>>(W1, W1b);
  f2b_kernel<<<2304, 256, 0, stream>>>(W2, W2b);
  bdist_t<<<8192, 256, 0, stream>>>(bdist, bdT);
  // 1) LN1 -> bf16
  ln_bf16<<<4096, 256, 0, stream>>>(x, ln1w, ln1b, xnb);
  // 2) qkv = xn @ W_in^T + b_in  (MFMA, fp32 out — round-3-proven)
  gemm_mfma<0, 0, 0><<<dim3(18, 32), 256, 0, stream>>>(
      xnb, DD, W_inb, DD, qkv, 3 * DD, b_in, nullptr, DD);
  // 3) pe_proj fp32 (round-3-proven)
  gemm_kernel<0><<<dim3(36, 2, 1), 256, 0, stream>>>(
      pe_emb, DD, 0, 0, W_in, DD, 0, 0, pe, 3 * DD, 0, 0, b_in, nullptr, DD, 0);
  // 4) split -> q,k fp32 + vb bf16
  split_qkv3<<<12288, 256, 0, stream>>>(qkv, q, k, vb);
  // 5) kp = k @ pe_q^T per head (round-3-proven math; bf16 store)
  gemm_kernel<1><<<dim3(2, 8, 96), 256, 0, stream>>>(
      k, DHH, (long)HH * LL * DHH, (long)LL * DHH,
      pe, 3 * DD, 0, 64,
      kpb, PP, (long)HH * LL * PP, (long)LL * PP, nullptr, nullptr, DHH, 0);
  // 6) qp = q @ pe_k^T per head
  gemm_kernel<1><<<dim3(2, 8, 96), 256, 0, stream>>>(
      q, DHH, (long)HH * LL * DHH, (long)LL * DHH,
      pe + DD, 3 * DD, 0, 64,
      qpb, PP, (long)HH * LL * PP, (long)LL * PP, nullptr, nullptr, DHH, 0);
  // 7) fused fp32 QK^T + LDS gathers + edge -> eout, + softmax tile stats
  qkt_gather_f32<<<dim3(8, 8, 96), 256, 0, stream>>>(q, k, kpb, qpb, bdT, edge,
                                                     eout, stats);
  // 8) fused softmax + PV -> olbd bf16 [L,B,D]
  softmax_pv_tiled<<<dim3(8, 96), 256, 0, stream>>>(eout, vb, stats, olbdb);
  // 9) x1 = O @ W_out^T + b_out + x
  gemm_mfma<0, 0, 1><<<dim3(6, 32), 256, 0, stream>>>(
      olbdb, DD, W_outb, DD, x1, DD, b_out, x, DD);
  // 10) LN2 -> bf16
  ln_bf16<<<4096, 256, 0, stream>>>(x1, ln2w, ln2b, xnb);
  // 11) ff1 = gelu(xn @ W1^T + b1) (bf16 out)
  gemm_mfma<1, 1, 0><<<dim3(24, 32), 256, 0, stream>>>(
      xnb, DD, W1b, DD, ff1b, 4 * DD, b1, nullptr, DD);
  // 12) x_out = ff1 @ W2^T + b2 + x1  (K=3072)
  gemm_mfma<0, 0, 1><<<dim3(6, 32), 256, 0, stream>>>(
      ff1b, 4 * DD, W2b, 4 * DD, xout, DD, b2, x1, 4 * DD);
}